// Round 4
// baseline (312.806 us; speedup 1.0000x reference)
//
#include <hip/hip_runtime.h>

#define N_NODES 6000
#define DEG_    16
#define N_EDGES (N_NODES*DEG_)
#define D_MODEL 256
#define D_MSG   64
#define D_FF    1024

typedef __bf16 bf16x8 __attribute__((ext_vector_type(8)));
typedef float floatx4 __attribute__((ext_vector_type(4)));

__device__ __forceinline__ float silu_f(float v) {
    return v * __builtin_amdgcn_rcpf(1.0f + __expf(-v));
}
__device__ __forceinline__ float b2f(unsigned short u) {
    union { unsigned int i; float f; } v; v.i = ((unsigned int)u) << 16; return v.f;
}
__device__ __forceinline__ unsigned short f2b(float f) {
    union { float f; unsigned int i; } v; v.f = f;
    unsigned int r = (v.i + 0x7FFFu + ((v.i >> 16) & 1u)) >> 16;
    return (unsigned short)r;
}

// ---------------- fused prep: weight cvt + embed + geom + Wcomb/wfc2/bias precompute ----------------
#define WSRC_OFF 0
#define WDST_OFF 49152
#define WEDGE_OFF 98304
#define W1_OFF 147456
#define W2_OFF 344064
#define WTOTAL 1130496
#define CVT4_BLOCKS (WTOTAL/4/256)             // 1104
#define EMB4_BLOCKS (N_NODES*D_MODEL/4/256)    // 1500
#define GEOM_BLOCKS (N_EDGES/256)              // 375
#define WCOMB_BLOCKS 256                       // 2 layers x 128 rows
#define WFC2_BLOCKS 4
__global__ __launch_bounds__(256) void prep_kernel(
    const float* __restrict__ Wsrc, const float* __restrict__ bsrc,
    const float* __restrict__ Wdst, const float* __restrict__ bdst,
    const float* __restrict__ Wedge, const float* __restrict__ W1,
    const float* __restrict__ W2, const float* __restrict__ b2,
    const float* __restrict__ Wfc, const float* __restrict__ bfc,
    unsigned short* __restrict__ wbf_out,
    const int* __restrict__ an, const float* __restrict__ emb,
    unsigned short* __restrict__ x,
    const float* __restrict__ r, float* __restrict__ d, float* __restrict__ rhat,
    unsigned short* __restrict__ wcomb, float* __restrict__ bcomb,
    float* __restrict__ wfc2, float* __restrict__ out) {
    int b = blockIdx.x;
    int t = threadIdx.x;
    if (b < CVT4_BLOCKS) {
        int i = (b*256 + t) * 4;
        const float* sp;
        if      (i < WDST_OFF)  sp = Wsrc + i;
        else if (i < WEDGE_OFF) sp = Wdst + (i - WDST_OFF);
        else if (i < W1_OFF)    sp = Wedge + (i - WEDGE_OFF);
        else if (i < W2_OFF)    sp = W1 + (i - W1_OFF);
        else                    sp = W2 + (i - W2_OFF);
        float4 v = *(const float4*)sp;
        *(ushort4*)(wbf_out + i) = make_ushort4(f2b(v.x), f2b(v.y), f2b(v.z), f2b(v.w));
    } else if (b < CVT4_BLOCKS + EMB4_BLOCKS) {
        int i4 = (b - CVT4_BLOCKS)*256 + t;
        int node = i4 >> 6, c4 = i4 & 63;
        float4 v = *(const float4*)(emb + (size_t)an[node]*D_MODEL + c4*4);
        *(ushort4*)(x + (size_t)node*D_MODEL + c4*4) =
            make_ushort4(f2b(v.x), f2b(v.y), f2b(v.z), f2b(v.w));
    } else if (b < CVT4_BLOCKS + EMB4_BLOCKS + GEOM_BLOCKS) {
        int e = (b - CVT4_BLOCKS - EMB4_BLOCKS)*256 + t;
        float xx = r[e*3+0], yy = r[e*3+1], zz = r[e*3+2];
        float n = sqrtf(xx*xx + yy*yy + zz*zz);
        d[e] = n;
        float inv = 1.0f / n;
        *(float4*)(rhat + (size_t)e*4) = make_float4(xx*inv, yy*inv, zz*inv, 0.f);
    } else if (b < CVT4_BLOCKS + EMB4_BLOCKS + GEOM_BLOCKS + WCOMB_BLOCKS) {
        int wb = b - (CVT4_BLOCKS + EMB4_BLOCKS + GEOM_BLOCKS);
        int lp  = 1 + (wb >> 7);
        int row = wb & 127;
        const float* wmrow = (row < 64) ? (Wsrc + (size_t)lp*16384 + row*256)
                                        : (Wdst + (size_t)lp*16384 + (row-64)*256);
        const float* W2f = W2 + (size_t)(lp-1)*262144;
        float a0 = 0.f, a1 = 0.f, a2 = 0.f, a3 = 0.f;
        int f = t*4;
        #pragma unroll 4
        for (int c = 0; c < 256; ++c) {
            float wm = wmrow[c];
            float4 w2v = *(const float4*)(W2f + (size_t)c*1024 + f);
            a0 = fmaf(wm, w2v.x, a0);
            a1 = fmaf(wm, w2v.y, a1);
            a2 = fmaf(wm, w2v.z, a2);
            a3 = fmaf(wm, w2v.w, a3);
        }
        *(ushort4*)(wcomb + (size_t)(lp-1)*131072 + (size_t)row*1024 + f) =
            make_ushort4(f2b(a0), f2b(a1), f2b(a2), f2b(a3));
    } else if (b < CVT4_BLOCKS + EMB4_BLOCKS + GEOM_BLOCKS + WCOMB_BLOCKS + WFC2_BLOCKS) {
        int wb = b - (CVT4_BLOCKS + EMB4_BLOCKS + GEOM_BLOCKS + WCOMB_BLOCKS);
        int c = wb*256 + t;
        const float* W2f = W2 + 2*262144;
        float acc = 0.f;
        for (int k = 0; k < 256; ++k) acc += Wfc[k] * W2f[(size_t)k*1024 + c];
        wfc2[c] = acc;
    } else {
        int lp = 1 + (t >> 7);
        int row = t & 127;
        const float* b2l = b2 + (lp-1)*256;
        const float* wmrow = (row < 64) ? (Wsrc + (size_t)lp*16384 + row*256)
                                        : (Wdst + (size_t)lp*16384 + (row-64)*256);
        float acc = 0.f;
        for (int c = 0; c < 256; ++c) acc += wmrow[c] * b2l[c];
        acc += (row < 64) ? bsrc[lp*64 + row] : bdst[lp*64 + (row-64)];
        bcomb[(lp-1)*128 + row] = acc;
        if (t == 0) {
            float bo = 0.f;
            const float* b23 = b2 + 2*256;
            for (int c = 0; c < 256; ++c) bo += Wfc[c] * b23[c];
            out[0] = bo + bfc[0];
        }
    }
}

// ---------------- eproj v2: [E,192] = RBF(d) @ Wedge^T + bedge, TM=64 (grid 1500) ----------------
#define EPITCH 264
__global__ __launch_bounds__(256) void eproj_kernel(
    const unsigned short* __restrict__ Bw,  // [192,256] bf16 (3 layers stacked)
    const float* __restrict__ bias,         // [192]
    const float* __restrict__ dvec,         // [E]
    unsigned short* __restrict__ C) {       // [E,192]
    __shared__ __align__(16) unsigned short As[64*EPITCH];  // 33792 B
    const int t = threadIdx.x;
    const int w = t >> 6, lane = t & 63, lr = lane & 15, lq = lane >> 4;
    const int m0 = blockIdx.x * 64;
    const int arow = t >> 2, achk = t & 3;

    float dv = dvec[m0 + arow];
    const float gamma = 31.875f;
    const float step  = 8.0f / 255.0f;
    #pragma unroll
    for (int c32 = 0; c32 < 8; ++c32) {
        int kb = c32*32 + achk*8;
        unsigned short h[8];
        #pragma unroll
        for (int j = 0; j < 8; ++j) {
            float tt = dv - (float)(kb+j)*step;
            h[j] = f2b(__expf(-gamma*tt*tt));
        }
        *(uint4*)(&As[arow*EPITCH + kb]) = *(uint4*)h;
    }
    __syncthreads();   // the only barrier in this kernel

    const unsigned short* Bbase = Bw + (size_t)(48*w + lr)*256 + lq*8;

    floatx4 acc[4][3] = {};
    uint4 pb[3];
    #pragma unroll
    for (int ns = 0; ns < 3; ++ns)
        pb[ns] = *(const uint4*)(Bbase + ns*16*256);

    for (int k0 = 0; k0 < 256; k0 += 32) {
        uint4 cb[3];
        cb[0] = pb[0]; cb[1] = pb[1]; cb[2] = pb[2];
        if (k0 + 32 < 256) {
            #pragma unroll
            for (int ns = 0; ns < 3; ++ns)
                pb[ns] = *(const uint4*)(Bbase + ns*16*256 + (k0+32));
        }
        bf16x8 af[4];
        #pragma unroll
        for (int mi = 0; mi < 4; ++mi)
            af[mi] = *(const bf16x8*)(&As[(mi*16 + lr)*EPITCH + k0 + lq*8]);
        #pragma unroll
        for (int mi = 0; mi < 4; ++mi) {
            #pragma unroll
            for (int ns = 0; ns < 3; ++ns)
                acc[mi][ns] = __builtin_amdgcn_mfma_f32_16x16x32_bf16(
                    af[mi], *(const bf16x8*)&cb[ns], acc[mi][ns], 0, 0, 0);
        }
    }

    #pragma unroll
    for (int ns = 0; ns < 3; ++ns) {
        int bc = 48*w + ns*16 + lr;
        float bv = bias[bc];
        #pragma unroll
        for (int mi = 0; mi < 4; ++mi) {
            #pragma unroll
            for (int rg = 0; rg < 4; ++rg) {
                int row = m0 + mi*16 + lq*4 + rg;
                C[(size_t)row*192 + bc] = f2b(acc[mi][ns][rg] + bv);
            }
        }
    }
}

// ---------------- MFMA bf16 GEMM v2: barrier-free, no LDS staging ----------------
// Key insight: the old LDS-staging pattern touched the SAME 64B global segments as
// direct fragment loads (A row=w*16+lr, k=lq*8), and A has no cross-wave reuse.
// So both A and B fragments load straight from global (B is L2-hot, 4x reuse via L2),
// register-prefetched one K-step ahead. Zero __syncthreads in the K-loop; direct
// global epilogue stores (32B segments, eproj-validated).
// ACT=0: plain+bias  ACT=1: silu+bias  ACT=2: silu+bias, dot wfc2, atomicAdd (fuses reduce2)
template<int ACT, int DUALB>
__global__ __launch_bounds__(256) void mgemm(
    const unsigned short* __restrict__ A, int lda,
    const unsigned short* __restrict__ B1, const unsigned short* __restrict__ B2, int ldb,
    const float* __restrict__ bias1, const float* __restrict__ bias2,
    unsigned short* __restrict__ C, int ldc, int M, int K) {
    __shared__ float red[256];           // ACT2 reduction only (1KB, no occupancy impact)
    const int t = threadIdx.x;
    const int w = t >> 6;
    const int lane = t & 63;
    const int lr = lane & 15;
    const int lq = lane >> 4;
    const int n0 = blockIdx.x * 64;
    const int m0 = blockIdx.y * 64;
    const unsigned short* B = B1;
    const float* bias = bias1;
    if (DUALB && blockIdx.x == 1) { B = B2; bias = bias2; }
    const unsigned short* Brow = DUALB ? B : (B + (size_t)n0*ldb);

    const int grow = m0 + w*16 + lr;          // global A row this lane supplies
    const bool rowok = grow < M;
    const unsigned short* Ap = A + (size_t)grow*lda + lq*8;
    const unsigned short* Bp = Brow + (size_t)lr*ldb + lq*8;

    floatx4 acc[4] = {};
    uint4 pa, pb[4];
    pa = rowok ? *(const uint4*)Ap : make_uint4(0,0,0,0);
    #pragma unroll
    for (int ns = 0; ns < 4; ++ns)
        pb[ns] = *(const uint4*)(Bp + (size_t)(ns*16)*ldb);

    for (int k0 = 0; k0 < K; k0 += 32) {
        uint4 ca = pa;
        uint4 cb0 = pb[0], cb1 = pb[1], cb2 = pb[2], cb3 = pb[3];
        if (k0 + 32 < K) {
            int kn = k0 + 32;
            pa = rowok ? *(const uint4*)(Ap + kn) : make_uint4(0,0,0,0);
            #pragma unroll
            for (int ns = 0; ns < 4; ++ns)
                pb[ns] = *(const uint4*)(Bp + (size_t)(ns*16)*ldb + kn);
        }
        bf16x8 af = *(const bf16x8*)&ca;
        acc[0] = __builtin_amdgcn_mfma_f32_16x16x32_bf16(af, *(const bf16x8*)&cb0, acc[0], 0,0,0);
        acc[1] = __builtin_amdgcn_mfma_f32_16x16x32_bf16(af, *(const bf16x8*)&cb1, acc[1], 0,0,0);
        acc[2] = __builtin_amdgcn_mfma_f32_16x16x32_bf16(af, *(const bf16x8*)&cb2, acc[2], 0,0,0);
        acc[3] = __builtin_amdgcn_mfma_f32_16x16x32_bf16(af, *(const bf16x8*)&cb3, acc[3], 0,0,0);
    }

    if (ACT == 2) {
        // fused FF(silu) . wfc2 partial reduction; no C store
        float partial = 0.f;
        #pragma unroll
        for (int ns = 0; ns < 4; ++ns) {
            int bc = ns*16 + lr;
            float bv = bias[n0 + bc];
            float wv = bias2[n0 + bc];
            #pragma unroll
            for (int rg = 0; rg < 4; ++rg) {
                int gm = m0 + w*16 + lq*4 + rg;
                float v = silu_f(acc[ns][rg] + bv);
                if (gm < M) partial += v * wv;
            }
        }
        red[t] = partial;
        __syncthreads();
        for (int off = 128; off > 0; off >>= 1) {
            if (t < off) red[t] += red[t+off];
            __syncthreads();
        }
        if (t == 0) atomicAdd((float*)C, red[0] * (1.0f/(float)N_NODES));
        return;
    }
    // direct global epilogue: per (ns,rg) store = 4 rows x 16 consecutive ushorts (32B segs)
    #pragma unroll
    for (int rg = 0; rg < 4; ++rg) {
        int gm = m0 + w*16 + lq*4 + rg;
        if (gm < M) {
            #pragma unroll
            for (int ns = 0; ns < 4; ++ns) {
                int bc = ns*16 + lr;
                float bv = bias[DUALB ? bc : (n0 + bc)];
                float v = acc[ns][rg] + bv;
                if (ACT) v = silu_f(v);
                C[(size_t)gm*ldc + n0 + bc] = f2b(v);
            }
        }
    }
}

// ---------------- angle attention, TWO nodes per block ----------------
__global__ __launch_bounds__(256) void angle_kernel(
    const unsigned short* __restrict__ xjxi,
    const unsigned short* __restrict__ eproj,
    const float* __restrict__ rhat,
    const int*   __restrict__ src,
    const float* __restrict__ attn,
    unsigned short* __restrict__ xn) {
    __shared__ __align__(16) float s_xij[2][16][68];
    __shared__ float s_rhat[2][16][4];
    __shared__ float s_logit[2][16][17];
    __shared__ float s_e[2][16][17];
    __shared__ float s_m[2][16], s_zi[2][16];
    __shared__ float s_w[2][16];
    const int t = threadIdx.x;
    const int h = t >> 7, tt = t & 127;
    const int node = blockIdx.x*2 + h;

    if (tt < 16) {
        float4 rv = *(const float4*)(rhat + (size_t)(node*DEG_ + tt)*4);
        s_rhat[h][tt][0] = rv.x; s_rhat[h][tt][1] = rv.y; s_rhat[h][tt][2] = rv.z; s_rhat[h][tt][3] = 0.f;
        s_e[h][tt][tt] = 0.f;
    }
    {
        int p = tt >> 3, c8 = tt & 7;
        int e = node*DEG_ + p;
        int se = src[e];
        uint4 aj = *(const uint4*)(xjxi + (size_t)se*128 + c8*8);
        uint4 ai = *(const uint4*)(xjxi + (size_t)node*128 + 64 + c8*8);
        uint4 ae = *(const uint4*)(eproj + (size_t)e*192 + c8*8);
        const unsigned short* pj = (const unsigned short*)&aj;
        const unsigned short* pi = (const unsigned short*)&ai;
        const unsigned short* pe = (const unsigned short*)&ae;
        #pragma unroll
        for (int j = 0; j < 8; ++j)
            s_xij[h][p][c8*8 + j] = b2f(pj[j]) + b2f(pi[j]) + b2f(pe[j]);
    }
    __syncthreads();
    int pp = 0, qq = 0;
    float lg = 0.f;
    if (tt < 120) {
        pp = (int)((1.0f + sqrtf(8.0f*(float)tt + 1.0f)) * 0.5f);
        qq = tt - ((pp*(pp-1)) >> 1);
        float c = s_rhat[h][pp][0]*s_rhat[h][qq][0] + s_rhat[h][pp][1]*s_rhat[h][qq][1]
                + s_rhat[h][pp][2]*s_rhat[h][qq][2];
        c = fminf(fmaxf(c, -0.999999f), 0.999999f);
        float c2  = 2.0f * c;
        float tk0 = 1.0f;
        float tk1 = c;
        float acc = 0.f;
        const float* xp = &s_xij[h][pp][0];
        const float* xq = &s_xij[h][qq][0];
        #pragma unroll
        for (int k0 = 0; k0 < 64; k0 += 4) {
            float4 xp4 = *(const float4*)(xp + k0);
            float4 xq4 = *(const float4*)(xq + k0);
            float a0 = attn[k0+0], a1 = attn[k0+1], a2 = attn[k0+2], a3 = attn[k0+3];
            float v0 = tk0 + xp4.x + xq4.x;
            acc = fmaf(a0, silu_f(v0), acc);
            { float tn2 = c2*tk1 - tk0; tk0 = tk1; tk1 = tn2; }
            float v1 = tk0 + xp4.y + xq4.y;
            acc = fmaf(a1, silu_f(v1), acc);
            { float tn2 = c2*tk1 - tk0; tk0 = tk1; tk1 = tn2; }
            float v2 = tk0 + xp4.z + xq4.z;
            acc = fmaf(a2, silu_f(v2), acc);
            { float tn2 = c2*tk1 - tk0; tk0 = tk1; tk1 = tn2; }
            float v3 = tk0 + xp4.w + xq4.w;
            acc = fmaf(a3, silu_f(v3), acc);
            { float tn2 = c2*tk1 - tk0; tk0 = tk1; tk1 = tn2; }
        }
        lg = acc;
        s_logit[h][pp][qq] = acc;
        s_logit[h][qq][pp] = acc;
    }
    __syncthreads();
    if (tt < 16) {
        int q = tt;
        float mx = -1e30f;
        #pragma unroll
        for (int p = 0; p < 16; ++p) if (p != q) mx = fmaxf(mx, s_logit[h][p][q]);
        s_m[h][q] = mx;
    }
    __syncthreads();
    if (tt < 120) {
        s_e[h][pp][qq] = __expf(lg - s_m[h][qq]);
        s_e[h][qq][pp] = __expf(lg - s_m[h][pp]);
    }
    __syncthreads();
    if (tt < 16) {
        int q = tt;
        float z = 0.f;
        #pragma unroll
        for (int p = 0; p < 16; ++p) z += s_e[h][p][q];
        s_zi[h][q] = __builtin_amdgcn_rcpf(z);
    }
    __syncthreads();
    if (tt < 16) {
        int p = tt;
        float sw = 0.f;
        #pragma unroll
        for (int q = 0; q < 16; ++q) sw += s_e[h][p][q] * s_zi[h][q];
        s_w[h][p] = sw;
    }
    __syncthreads();
    if (tt < 64) {
        float acc = 0.f;
        #pragma unroll
        for (int p = 0; p < 16; ++p) acc += s_w[h][p] * s_xij[h][p][tt];
        xn[(size_t)node*64 + tt] = f2b(acc);
    }
}

extern "C" void kernel_launch(void* const* d_in, const int* in_sizes, int n_in,
                              void* d_out, int out_size, void* d_ws, size_t ws_size,
                              hipStream_t stream) {
    (void)in_sizes; (void)n_in; (void)out_size; (void)ws_size;
    const float* r    = (const float*)d_in[0];
    const int*   an   = (const int*)  d_in[1];
    const int*   src  = (const int*)  d_in[2];
    const float* emb  = (const float*)d_in[6];
    const float* Wsrc = (const float*)d_in[7];
    const float* bsrc = (const float*)d_in[8];
    const float* Wdst = (const float*)d_in[9];
    const float* bdst = (const float*)d_in[10];
    const float* Wedge= (const float*)d_in[11];
    const float* bedge= (const float*)d_in[12];
    const float* attn = (const float*)d_in[13];
    const float* W1   = (const float*)d_in[14];
    const float* b1   = (const float*)d_in[15];
    const float* W2   = (const float*)d_in[16];
    const float* b2   = (const float*)d_in[17];
    const float* Wfc  = (const float*)d_in[18];
    const float* bfc  = (const float*)d_in[19];

    char* ws = (char*)d_ws;
    float* d_d              = (float*)(ws);                    // 384000 B
    float* d_rhat           = (float*)(ws + 384000);           // 1536000 B
    unsigned short* wbf     = (unsigned short*)(ws + 1920000); // 2260992 B
    unsigned short* d_x     = (unsigned short*)(ws + 4180992); // 3072000 B
    unsigned short* d_xjxi  = (unsigned short*)(ws + 7252992); // 1536000 B
    unsigned short* d_eproj = (unsigned short*)(ws + 8788992); // 36864000 B
    unsigned short* d_xn    = (unsigned short*)(ws + 45652992);// 768000 B
    unsigned short* d_h     = (unsigned short*)(ws + 46420992);// 12288000 B
    unsigned short* d_wcomb = (unsigned short*)(ws + 58708992);// 524288 B
    float* d_bcomb          = (float*)(ws + 59233280);         // 1024 B
    float* d_wfc2           = (float*)(ws + 59234304);         // 4096 B
    float* out = (float*)d_out;

    unsigned short* wsrc_bf  = wbf + WSRC_OFF;
    unsigned short* wdst_bf  = wbf + WDST_OFF;
    unsigned short* wedge_bf = wbf + WEDGE_OFF;
    unsigned short* w1_bf    = wbf + W1_OFF;

    prep_kernel<<<CVT4_BLOCKS + EMB4_BLOCKS + GEOM_BLOCKS + WCOMB_BLOCKS + WFC2_BLOCKS + 1,
                  256, 0, stream>>>(
        Wsrc, bsrc, Wdst, bdst, Wedge, W1, W2, b2, Wfc, bfc,
        wbf, an, emb, d_x, r, d_d, d_rhat, d_wcomb, d_bcomb, d_wfc2, out);
    eproj_kernel<<<1500, 256, 0, stream>>>(wedge_bf, bedge, d_d, d_eproj);

    // ---- layer 0 ----
    mgemm<0,1><<<dim3(2,94), 256, 0, stream>>>(
        d_x, 256, wsrc_bf, wdst_bf, 256,
        bsrc, bdst, d_xjxi, 128, N_NODES, 256);
    angle_kernel<<<N_NODES/2, 256, 0, stream>>>(
        d_xjxi, d_eproj, d_rhat, src, attn, d_xn);
    mgemm<1,0><<<dim3(16,94), 256, 0, stream>>>(
        d_xn, 64, w1_bf, (const unsigned short*)nullptr, 64,
        b1, (const float*)nullptr, d_h, D_FF, N_NODES, 64);
    mgemm<0,0><<<dim3(2,94), 256, 0, stream>>>(
        d_h, 1024, d_wcomb, (const unsigned short*)nullptr, 1024,
        d_bcomb, (const float*)nullptr, d_xjxi, 128, N_NODES, 1024);

    // ---- layer 1 ----
    angle_kernel<<<N_NODES/2, 256, 0, stream>>>(
        d_xjxi, d_eproj + 64, d_rhat, src, attn + 64, d_xn);
    mgemm<1,0><<<dim3(16,94), 256, 0, stream>>>(
        d_xn, 64, w1_bf + 65536, (const unsigned short*)nullptr, 64,
        b1 + 1024, (const float*)nullptr, d_h, D_FF, N_NODES, 64);
    mgemm<0,0><<<dim3(2,94), 256, 0, stream>>>(
        d_h, 1024, d_wcomb + 131072, (const unsigned short*)nullptr, 1024,
        d_bcomb + 128, (const float*)nullptr, d_xjxi, 128, N_NODES, 1024);

    // ---- layer 2 (FF fused with final reduction; no d_h store, no reduce2) ----
    angle_kernel<<<N_NODES/2, 256, 0, stream>>>(
        d_xjxi, d_eproj + 128, d_rhat, src, attn + 128, d_xn);
    mgemm<2,0><<<dim3(16,94), 256, 0, stream>>>(
        d_xn, 64, w1_bf + 131072, (const unsigned short*)nullptr, 64,
        b1 + 2048, d_wfc2, (unsigned short*)out, 0, N_NODES, 64);
}

// Round 5
// 286.022 us; speedup vs baseline: 1.0936x; 1.0936x over previous
//
#include <hip/hip_runtime.h>

#define N_NODES 6000
#define DEG_    16
#define N_EDGES (N_NODES*DEG_)
#define D_MODEL 256
#define D_MSG   64
#define D_FF    1024

typedef __bf16 bf16x8 __attribute__((ext_vector_type(8)));
typedef float floatx4 __attribute__((ext_vector_type(4)));

__device__ __forceinline__ float silu_f(float v) {
    return v * __builtin_amdgcn_rcpf(1.0f + __expf(-v));
}
__device__ __forceinline__ float b2f(unsigned short u) {
    union { unsigned int i; float f; } v; v.i = ((unsigned int)u) << 16; return v.f;
}
__device__ __forceinline__ unsigned short f2b(float f) {
    union { float f; unsigned int i; } v; v.f = f;
    unsigned int r = (v.i + 0x7FFFu + ((v.i >> 16) & 1u)) >> 16;
    return (unsigned short)r;
}

// ---------------- fused prep: weight cvt + embed + geom + Wcomb/wfc2/bias precompute ----------------
#define WSRC_OFF 0
#define WDST_OFF 49152
#define WEDGE_OFF 98304
#define W1_OFF 147456
#define W2_OFF 344064
#define WTOTAL 1130496
#define CVT4_BLOCKS (WTOTAL/4/256)             // 1104
#define EMB4_BLOCKS (N_NODES*D_MODEL/4/256)    // 1500
#define GEOM_BLOCKS (N_EDGES/256)              // 375
#define WCOMB_BLOCKS 256                       // 2 layers x 128 rows
#define WFC2_BLOCKS 4
__global__ __launch_bounds__(256) void prep_kernel(
    const float* __restrict__ Wsrc, const float* __restrict__ bsrc,
    const float* __restrict__ Wdst, const float* __restrict__ bdst,
    const float* __restrict__ Wedge, const float* __restrict__ W1,
    const float* __restrict__ W2, const float* __restrict__ b2,
    const float* __restrict__ Wfc, const float* __restrict__ bfc,
    unsigned short* __restrict__ wbf_out,
    const int* __restrict__ an, const float* __restrict__ emb,
    unsigned short* __restrict__ x,
    const float* __restrict__ r, float* __restrict__ d, float* __restrict__ rhat,
    unsigned short* __restrict__ wcomb, float* __restrict__ bcomb,
    float* __restrict__ wfc2, float* __restrict__ out) {
    int b = blockIdx.x;
    int t = threadIdx.x;
    if (b < CVT4_BLOCKS) {
        int i = (b*256 + t) * 4;
        const float* sp;
        if      (i < WDST_OFF)  sp = Wsrc + i;
        else if (i < WEDGE_OFF) sp = Wdst + (i - WDST_OFF);
        else if (i < W1_OFF)    sp = Wedge + (i - WEDGE_OFF);
        else if (i < W2_OFF)    sp = W1 + (i - W1_OFF);
        else                    sp = W2 + (i - W2_OFF);
        float4 v = *(const float4*)sp;
        *(ushort4*)(wbf_out + i) = make_ushort4(f2b(v.x), f2b(v.y), f2b(v.z), f2b(v.w));
    } else if (b < CVT4_BLOCKS + EMB4_BLOCKS) {
        int i4 = (b - CVT4_BLOCKS)*256 + t;
        int node = i4 >> 6, c4 = i4 & 63;
        float4 v = *(const float4*)(emb + (size_t)an[node]*D_MODEL + c4*4);
        *(ushort4*)(x + (size_t)node*D_MODEL + c4*4) =
            make_ushort4(f2b(v.x), f2b(v.y), f2b(v.z), f2b(v.w));
    } else if (b < CVT4_BLOCKS + EMB4_BLOCKS + GEOM_BLOCKS) {
        int e = (b - CVT4_BLOCKS - EMB4_BLOCKS)*256 + t;
        float xx = r[e*3+0], yy = r[e*3+1], zz = r[e*3+2];
        float n = sqrtf(xx*xx + yy*yy + zz*zz);
        d[e] = n;
        float inv = 1.0f / n;
        *(float4*)(rhat + (size_t)e*4) = make_float4(xx*inv, yy*inv, zz*inv, 0.f);
    } else if (b < CVT4_BLOCKS + EMB4_BLOCKS + GEOM_BLOCKS + WCOMB_BLOCKS) {
        int wb = b - (CVT4_BLOCKS + EMB4_BLOCKS + GEOM_BLOCKS);
        int lp  = 1 + (wb >> 7);
        int row = wb & 127;
        const float* wmrow = (row < 64) ? (Wsrc + (size_t)lp*16384 + row*256)
                                        : (Wdst + (size_t)lp*16384 + (row-64)*256);
        const float* W2f = W2 + (size_t)(lp-1)*262144;
        float a0 = 0.f, a1 = 0.f, a2 = 0.f, a3 = 0.f;
        int f = t*4;
        #pragma unroll 4
        for (int c = 0; c < 256; ++c) {
            float wm = wmrow[c];
            float4 w2v = *(const float4*)(W2f + (size_t)c*1024 + f);
            a0 = fmaf(wm, w2v.x, a0);
            a1 = fmaf(wm, w2v.y, a1);
            a2 = fmaf(wm, w2v.z, a2);
            a3 = fmaf(wm, w2v.w, a3);
        }
        *(ushort4*)(wcomb + (size_t)(lp-1)*131072 + (size_t)row*1024 + f) =
            make_ushort4(f2b(a0), f2b(a1), f2b(a2), f2b(a3));
    } else if (b < CVT4_BLOCKS + EMB4_BLOCKS + GEOM_BLOCKS + WCOMB_BLOCKS + WFC2_BLOCKS) {
        int wb = b - (CVT4_BLOCKS + EMB4_BLOCKS + GEOM_BLOCKS + WCOMB_BLOCKS);
        int c = wb*256 + t;
        const float* W2f = W2 + 2*262144;
        float acc = 0.f;
        for (int k = 0; k < 256; ++k) acc += Wfc[k] * W2f[(size_t)k*1024 + c];
        wfc2[c] = acc;
    } else {
        int lp = 1 + (t >> 7);
        int row = t & 127;
        const float* b2l = b2 + (lp-1)*256;
        const float* wmrow = (row < 64) ? (Wsrc + (size_t)lp*16384 + row*256)
                                        : (Wdst + (size_t)lp*16384 + (row-64)*256);
        float acc = 0.f;
        for (int c = 0; c < 256; ++c) acc += wmrow[c] * b2l[c];
        acc += (row < 64) ? bsrc[lp*64 + row] : bdst[lp*64 + (row-64)];
        bcomb[(lp-1)*128 + row] = acc;
        if (t == 0) {
            float bo = 0.f;
            const float* b23 = b2 + 2*256;
            for (int c = 0; c < 256; ++c) bo += Wfc[c] * b23[c];
            out[0] = bo + bfc[0];
        }
    }
}

// ---------------- merged eproj + layer0 xj/xi GEMM (both depend only on prep) ----------------
// blocks [0,1500): eproj v2 (round-3 proven body)
// blocks [1500,1688): LDS-staged dual-B GEMM (round-3 mgemm<0,1> body), overlaps eproj tail
#define EPITCH 264
#define APITCH 40
#define MCP 72
__global__ __launch_bounds__(256) void eplg_kernel(
    const unsigned short* __restrict__ Bw,  // [192,256] Wedge bf16 (3 layers stacked)
    const float* __restrict__ bias,         // bedge [192]
    const float* __restrict__ dvec,         // [E]
    unsigned short* __restrict__ C,         // eproj out [E,192]
    const unsigned short* __restrict__ A,   // d_x [N,256]
    const unsigned short* __restrict__ B1g, // wsrc [64,256]
    const unsigned short* __restrict__ B2g, // wdst [64,256]
    const float* __restrict__ bias1,        // bsrc
    const float* __restrict__ bias2,        // bdst
    unsigned short* __restrict__ Cg) {      // d_xjxi [N,128]
    __shared__ __align__(16) unsigned short sm[64*EPITCH];   // 33792 B (union)
    const int t = threadIdx.x;
    const int w = t >> 6, lane = t & 63, lr = lane & 15, lq = lane >> 4;

    if (blockIdx.x < 1500) {
        // ================= eproj =================
        unsigned short* As = sm;
        const int m0 = blockIdx.x * 64;
        const int arow = t >> 2, achk = t & 3;

        float dv = dvec[m0 + arow];
        const float gamma = 31.875f;
        const float step  = 8.0f / 255.0f;
        #pragma unroll
        for (int c32 = 0; c32 < 8; ++c32) {
            int kb = c32*32 + achk*8;
            unsigned short h[8];
            #pragma unroll
            for (int j = 0; j < 8; ++j) {
                float tt = dv - (float)(kb+j)*step;
                h[j] = f2b(__expf(-gamma*tt*tt));
            }
            *(uint4*)(&As[arow*EPITCH + kb]) = *(uint4*)h;
        }
        __syncthreads();

        const unsigned short* Bbase = Bw + (size_t)(48*w + lr)*256 + lq*8;

        floatx4 acc[4][3] = {};
        uint4 pb[3];
        #pragma unroll
        for (int ns = 0; ns < 3; ++ns)
            pb[ns] = *(const uint4*)(Bbase + ns*16*256);

        for (int k0 = 0; k0 < 256; k0 += 32) {
            uint4 cb[3];
            cb[0] = pb[0]; cb[1] = pb[1]; cb[2] = pb[2];
            if (k0 + 32 < 256) {
                #pragma unroll
                for (int ns = 0; ns < 3; ++ns)
                    pb[ns] = *(const uint4*)(Bbase + ns*16*256 + (k0+32));
            }
            bf16x8 af[4];
            #pragma unroll
            for (int mi = 0; mi < 4; ++mi)
                af[mi] = *(const bf16x8*)(&As[(mi*16 + lr)*EPITCH + k0 + lq*8]);
            #pragma unroll
            for (int mi = 0; mi < 4; ++mi) {
                #pragma unroll
                for (int ns = 0; ns < 3; ++ns)
                    acc[mi][ns] = __builtin_amdgcn_mfma_f32_16x16x32_bf16(
                        af[mi], *(const bf16x8*)&cb[ns], acc[mi][ns], 0, 0, 0);
            }
        }

        #pragma unroll
        for (int ns = 0; ns < 3; ++ns) {
            int bc = 48*w + ns*16 + lr;
            float bv = bias[bc];
            #pragma unroll
            for (int mi = 0; mi < 4; ++mi) {
                #pragma unroll
                for (int rg = 0; rg < 4; ++rg) {
                    int row = m0 + mi*16 + lq*4 + rg;
                    C[(size_t)row*192 + bc] = f2b(acc[mi][ns][rg] + bv);
                }
            }
        }
        return;
    }
    // ================= layer0 dual-B GEMM (K=256, M=6000) =================
    {
        unsigned short* As = sm;          // 64*40
        unsigned short* Bs = sm + 2560;   // 64*40
        unsigned short* Cs = sm;          // 64*72 epilogue reuse
        const int bid2 = blockIdx.x - 1500;
        const int bx = bid2 & 1;
        const int m0 = (bid2 >> 1) * 64;
        const unsigned short* B = bx ? B2g : B1g;
        const float* biasl = bx ? bias2 : bias1;
        const int n0 = bx * 64;
        const int K = 256, M = N_NODES, lda = 256, ldb = 256, ldc = 128;

        const int arow = t >> 2, achk = t & 3;

        floatx4 acc[4] = {};
        uint4 pa, pb;
        {
            int gm = m0 + arow;
            pa = (gm < M) ? *(const uint4*)(A + (size_t)gm*lda + achk*8) : make_uint4(0,0,0,0);
        }
        pb = *(const uint4*)(B + (size_t)arow*ldb + achk*8);

        for (int k0 = 0; k0 < K; k0 += 32) {
            *(uint4*)(&As[arow*APITCH + achk*8]) = pa;
            *(uint4*)(&Bs[arow*APITCH + achk*8]) = pb;
            __syncthreads();
            if (k0 + 32 < K) {
                int kn = k0 + 32;
                int gm = m0 + arow;
                pa = (gm < M) ? *(const uint4*)(A + (size_t)gm*lda + kn + achk*8) : make_uint4(0,0,0,0);
                pb = *(const uint4*)(B + (size_t)arow*ldb + kn + achk*8);
            }
            bf16x8 af, bfr[4];
            af = *(const bf16x8*)(&As[(w*16 + lr)*APITCH + lq*8]);
            #pragma unroll
            for (int ns = 0; ns < 4; ++ns)
                bfr[ns] = *(const bf16x8*)(&Bs[(ns*16 + lr)*APITCH + lq*8]);
            #pragma unroll
            for (int ns = 0; ns < 4; ++ns)
                acc[ns] = __builtin_amdgcn_mfma_f32_16x16x32_bf16(af, bfr[ns], acc[ns], 0,0,0);
            __syncthreads();
        }
        #pragma unroll
        for (int ns = 0; ns < 4; ++ns) {
            int bc = ns*16 + lr;
            float bv = biasl[bc];
            #pragma unroll
            for (int rg = 0; rg < 4; ++rg) {
                int lrow = w*16 + lq*4 + rg;
                Cs[lrow*MCP + bc] = f2b(acc[ns][rg] + bv);
            }
        }
        __syncthreads();
        #pragma unroll
        for (int it = 0; it < 2; ++it) {
            int i = t + it*256;
            int row = i >> 3, c8 = i & 7;
            int gm = m0 + row;
            if (gm < M)
                *(uint4*)(Cg + (size_t)gm*ldc + n0 + c8*8) = *(const uint4*)(Cs + row*MCP + c8*8);
        }
    }
}

// ---------------- MFMA bf16 GEMM (round-3 LDS version; used for layer-2 FF+reduce) ----------------
template<int ACT, int DUALB>
__global__ __launch_bounds__(256) void mgemm(
    const unsigned short* __restrict__ A, int lda,
    const unsigned short* __restrict__ B1, const unsigned short* __restrict__ B2, int ldb,
    const float* __restrict__ bias1, const float* __restrict__ bias2,
    unsigned short* __restrict__ C, int ldc, int M, int K) {
    __shared__ __align__(16) unsigned short sm[5120];
    unsigned short* As = sm;
    unsigned short* Bs = sm + 2560;
    unsigned short* Cs = sm;
    const int t = threadIdx.x;
    const int w = t >> 6;
    const int lane = t & 63;
    const int lr = lane & 15;
    const int lq = lane >> 4;
    const int n0 = blockIdx.x * 64;
    const int m0 = blockIdx.y * 64;
    const unsigned short* B = B1;
    const float* bias = bias1;
    if (DUALB && blockIdx.x == 1) { B = B2; bias = bias2; }
    const unsigned short* Brow = DUALB ? B : (B + (size_t)n0*ldb);

    const int arow = t >> 2, achk = t & 3;

    floatx4 acc[4] = {};
    uint4 pa, pb;
    {
        int gm = m0 + arow;
        pa = (gm < M) ? *(const uint4*)(A + (size_t)gm*lda + achk*8) : make_uint4(0,0,0,0);
    }
    pb = *(const uint4*)(Brow + (size_t)arow*ldb + achk*8);

    for (int k0 = 0; k0 < K; k0 += 32) {
        *(uint4*)(&As[arow*APITCH + achk*8]) = pa;
        *(uint4*)(&Bs[arow*APITCH + achk*8]) = pb;
        __syncthreads();
        if (k0 + 32 < K) {
            int kn = k0 + 32;
            int gm = m0 + arow;
            pa = (gm < M) ? *(const uint4*)(A + (size_t)gm*lda + kn + achk*8) : make_uint4(0,0,0,0);
            pb = *(const uint4*)(Brow + (size_t)arow*ldb + kn + achk*8);
        }
        bf16x8 af, bfr[4];
        af = *(const bf16x8*)(&As[(w*16 + lr)*APITCH + lq*8]);
        #pragma unroll
        for (int ns = 0; ns < 4; ++ns)
            bfr[ns] = *(const bf16x8*)(&Bs[(ns*16 + lr)*APITCH + lq*8]);
        #pragma unroll
        for (int ns = 0; ns < 4; ++ns)
            acc[ns] = __builtin_amdgcn_mfma_f32_16x16x32_bf16(af, bfr[ns], acc[ns], 0,0,0);
        __syncthreads();
    }
    if (ACT == 2) {
        float partial = 0.f;
        #pragma unroll
        for (int ns = 0; ns < 4; ++ns) {
            int bc = ns*16 + lr;
            float bv = bias[n0 + bc];
            float wv = bias2[n0 + bc];
            #pragma unroll
            for (int rg = 0; rg < 4; ++rg) {
                int gm = m0 + w*16 + lq*4 + rg;
                float v = silu_f(acc[ns][rg] + bv);
                if (gm < M) partial += v * wv;
            }
        }
        float* red = (float*)sm;
        red[t] = partial;
        __syncthreads();
        for (int off = 128; off > 0; off >>= 1) {
            if (t < off) red[t] += red[t+off];
            __syncthreads();
        }
        if (t == 0) atomicAdd((float*)C, red[0] * (1.0f/(float)N_NODES));
        return;
    }
    #pragma unroll
    for (int ns = 0; ns < 4; ++ns) {
        int bc = ns*16 + lr;
        float bv = bias[DUALB ? bc : (n0 + bc)];
        #pragma unroll
        for (int rg = 0; rg < 4; ++rg) {
            int lrow = w*16 + lq*4 + rg;
            float v = acc[ns][rg] + bv;
            if (ACT) v = silu_f(v);
            Cs[lrow*MCP + bc] = f2b(v);
        }
    }
    __syncthreads();
    #pragma unroll
    for (int it = 0; it < 2; ++it) {
        int i = t + it*256;
        int row = i >> 3, c8 = i & 7;
        int gm = m0 + row;
        if (gm < M)
            *(uint4*)(C + (size_t)gm*ldc + n0 + c8*8) = *(const uint4*)(Cs + row*MCP + c8*8);
    }
}

// ---------------- fused FF + wcomb: xjxi[16 nodes,128] = silu(xn@W1^T+b1) @ wcomb^T + bcomb ----
// The FF->wcomb dependency is node-local: one block owns 16 nodes end-to-end, h stays
// in LDS chunk-by-chunk (16 chunks of 64 ff-cols), d_h round-trip eliminated.
// 375 blocks. B-chunks (W1 128KB, wcomb 256KB) are L2-hot; next-chunk register prefetch.
#define HP 72
#define CP2 136
__global__ __launch_bounds__(256) void ffw_kernel(
    const unsigned short* __restrict__ XN,   // [N,64] bf16
    const unsigned short* __restrict__ W1l,  // [1024,64] bf16
    const float* __restrict__ b1l,           // [1024]
    const unsigned short* __restrict__ WC,   // [128,1024] bf16
    const float* __restrict__ bcl,           // [128]
    unsigned short* __restrict__ XO,         // [N,128] bf16
    int M) {
    __shared__ __align__(16) unsigned short s_h[16*HP];    // h chunk [16][72]
    __shared__ __align__(16) unsigned short s_c[16*CP2];   // epilogue [16][136]
    const int t = threadIdx.x;
    const int wv = t >> 6, lane = t & 63, lr = lane & 15, lq = lane >> 4;
    const int m0 = blockIdx.x * 16;

    // A fragments (xn rows m0+lr), reused across all chunks; same for all 4 waves
    int ga = m0 + lr;
    bool aok = ga < M;
    uint4 a0 = aok ? *(const uint4*)(XN + (size_t)ga*64 + lq*8) : make_uint4(0,0,0,0);
    uint4 a1 = aok ? *(const uint4*)(XN + (size_t)ga*64 + 32 + lq*8) : make_uint4(0,0,0,0);

    floatx4 acc2[2] = {};   // [16 rows x 32 cols] per wave, accumulated over all 16 chunks

    // prefetch chunk 0
    const unsigned short* B1base = W1l + (size_t)(wv*16 + lr)*64 + lq*8;       // + f*64*64
    const unsigned short* B2base = WC + (size_t)(wv*32 + lr)*1024 + lq*8;      // + f*64
    uint4 pb1[2], pb2[4];
    pb1[0] = *(const uint4*)(B1base);
    pb1[1] = *(const uint4*)(B1base + 32);
    pb2[0] = *(const uint4*)(B2base);
    pb2[1] = *(const uint4*)(B2base + 32);
    pb2[2] = *(const uint4*)(B2base + 16*1024);
    pb2[3] = *(const uint4*)(B2base + 16*1024 + 32);

    for (int f = 0; f < 16; ++f) {
        uint4 cb1_0 = pb1[0], cb1_1 = pb1[1];
        uint4 cb2_0 = pb2[0], cb2_1 = pb2[1], cb2_2 = pb2[2], cb2_3 = pb2[3];
        float bv1 = b1l[f*64 + wv*16 + lr];
        if (f < 15) {
            const unsigned short* n1 = B1base + (size_t)(f+1)*64*64;
            const unsigned short* n2 = B2base + (f+1)*64;
            pb1[0] = *(const uint4*)(n1);
            pb1[1] = *(const uint4*)(n1 + 32);
            pb2[0] = *(const uint4*)(n2);
            pb2[1] = *(const uint4*)(n2 + 32);
            pb2[2] = *(const uint4*)(n2 + 16*1024);
            pb2[3] = *(const uint4*)(n2 + 16*1024 + 32);
        }
        // ---- first GEMM: h chunk [16 nodes x 64 ff], wave wv owns 16 ff-cols ----
        floatx4 hacc = {};
        hacc = __builtin_amdgcn_mfma_f32_16x16x32_bf16(
            *(const bf16x8*)&a0, *(const bf16x8*)&cb1_0, hacc, 0,0,0);
        hacc = __builtin_amdgcn_mfma_f32_16x16x32_bf16(
            *(const bf16x8*)&a1, *(const bf16x8*)&cb1_1, hacc, 0,0,0);
        {
            int col = wv*16 + lr;
            #pragma unroll
            for (int rg = 0; rg < 4; ++rg) {
                int row = lq*4 + rg;
                s_h[row*HP + col] = f2b(silu_f(hacc[rg] + bv1));
            }
        }
        __syncthreads();
        // ---- second GEMM: acc2 += h_chunk @ wcomb_chunk^T, wave wv owns 32 out-cols ----
        bf16x8 ha0 = *(const bf16x8*)(&s_h[lr*HP + lq*8]);
        bf16x8 ha1 = *(const bf16x8*)(&s_h[lr*HP + 32 + lq*8]);
        acc2[0] = __builtin_amdgcn_mfma_f32_16x16x32_bf16(ha0, *(const bf16x8*)&cb2_0, acc2[0], 0,0,0);
        acc2[0] = __builtin_amdgcn_mfma_f32_16x16x32_bf16(ha1, *(const bf16x8*)&cb2_1, acc2[0], 0,0,0);
        acc2[1] = __builtin_amdgcn_mfma_f32_16x16x32_bf16(ha0, *(const bf16x8*)&cb2_2, acc2[1], 0,0,0);
        acc2[1] = __builtin_amdgcn_mfma_f32_16x16x32_bf16(ha1, *(const bf16x8*)&cb2_3, acc2[1], 0,0,0);
        __syncthreads();   // protect s_h before next chunk overwrites
    }

    // epilogue: bias + coalesced store via LDS
    #pragma unroll
    for (int ns = 0; ns < 2; ++ns) {
        int col = wv*32 + ns*16 + lr;
        float bv = bcl[col];
        #pragma unroll
        for (int rg = 0; rg < 4; ++rg) {
            int row = lq*4 + rg;
            s_c[row*CP2 + col] = f2b(acc2[ns][rg] + bv);
        }
    }
    __syncthreads();
    {
        int row = t >> 4, c8 = t & 15;   // 256 threads = 16 rows x 16 uint4
        int gm = m0 + row;
        if (gm < M)
            *(uint4*)(XO + (size_t)gm*128 + c8*8) = *(const uint4*)(s_c + row*CP2 + c8*8);
    }
}

// ---------------- angle attention, TWO nodes per block ----------------
__global__ __launch_bounds__(256) void angle_kernel(
    const unsigned short* __restrict__ xjxi,
    const unsigned short* __restrict__ eproj,
    const float* __restrict__ rhat,
    const int*   __restrict__ src,
    const float* __restrict__ attn,
    unsigned short* __restrict__ xn) {
    __shared__ __align__(16) float s_xij[2][16][68];
    __shared__ float s_rhat[2][16][4];
    __shared__ float s_logit[2][16][17];
    __shared__ float s_e[2][16][17];
    __shared__ float s_m[2][16], s_zi[2][16];
    __shared__ float s_w[2][16];
    const int t = threadIdx.x;
    const int h = t >> 7, tt = t & 127;
    const int node = blockIdx.x*2 + h;

    if (tt < 16) {
        float4 rv = *(const float4*)(rhat + (size_t)(node*DEG_ + tt)*4);
        s_rhat[h][tt][0] = rv.x; s_rhat[h][tt][1] = rv.y; s_rhat[h][tt][2] = rv.z; s_rhat[h][tt][3] = 0.f;
        s_e[h][tt][tt] = 0.f;
    }
    {
        int p = tt >> 3, c8 = tt & 7;
        int e = node*DEG_ + p;
        int se = src[e];
        uint4 aj = *(const uint4*)(xjxi + (size_t)se*128 + c8*8);
        uint4 ai = *(const uint4*)(xjxi + (size_t)node*128 + 64 + c8*8);
        uint4 ae = *(const uint4*)(eproj + (size_t)e*192 + c8*8);
        const unsigned short* pj = (const unsigned short*)&aj;
        const unsigned short* pi = (const unsigned short*)&ai;
        const unsigned short* pe = (const unsigned short*)&ae;
        #pragma unroll
        for (int j = 0; j < 8; ++j)
            s_xij[h][p][c8*8 + j] = b2f(pj[j]) + b2f(pi[j]) + b2f(pe[j]);
    }
    __syncthreads();
    int pp = 0, qq = 0;
    float lg = 0.f;
    if (tt < 120) {
        pp = (int)((1.0f + sqrtf(8.0f*(float)tt + 1.0f)) * 0.5f);
        qq = tt - ((pp*(pp-1)) >> 1);
        float c = s_rhat[h][pp][0]*s_rhat[h][qq][0] + s_rhat[h][pp][1]*s_rhat[h][qq][1]
                + s_rhat[h][pp][2]*s_rhat[h][qq][2];
        c = fminf(fmaxf(c, -0.999999f), 0.999999f);
        float c2  = 2.0f * c;
        float tk0 = 1.0f;
        float tk1 = c;
        float acc = 0.f;
        const float* xp = &s_xij[h][pp][0];
        const float* xq = &s_xij[h][qq][0];
        #pragma unroll
        for (int k0 = 0; k0 < 64; k0 += 4) {
            float4 xp4 = *(const float4*)(xp + k0);
            float4 xq4 = *(const float4*)(xq + k0);
            float a0 = attn[k0+0], a1 = attn[k0+1], a2 = attn[k0+2], a3 = attn[k0+3];
            float v0 = tk0 + xp4.x + xq4.x;
            acc = fmaf(a0, silu_f(v0), acc);
            { float tn2 = c2*tk1 - tk0; tk0 = tk1; tk1 = tn2; }
            float v1 = tk0 + xp4.y + xq4.y;
            acc = fmaf(a1, silu_f(v1), acc);
            { float tn2 = c2*tk1 - tk0; tk0 = tk1; tk1 = tn2; }
            float v2 = tk0 + xp4.z + xq4.z;
            acc = fmaf(a2, silu_f(v2), acc);
            { float tn2 = c2*tk1 - tk0; tk0 = tk1; tk1 = tn2; }
            float v3 = tk0 + xp4.w + xq4.w;
            acc = fmaf(a3, silu_f(v3), acc);
            { float tn2 = c2*tk1 - tk0; tk0 = tk1; tk1 = tn2; }
        }
        lg = acc;
        s_logit[h][pp][qq] = acc;
        s_logit[h][qq][pp] = acc;
    }
    __syncthreads();
    if (tt < 16) {
        int q = tt;
        float mx = -1e30f;
        #pragma unroll
        for (int p = 0; p < 16; ++p) if (p != q) mx = fmaxf(mx, s_logit[h][p][q]);
        s_m[h][q] = mx;
    }
    __syncthreads();
    if (tt < 120) {
        s_e[h][pp][qq] = __expf(lg - s_m[h][qq]);
        s_e[h][qq][pp] = __expf(lg - s_m[h][pp]);
    }
    __syncthreads();
    if (tt < 16) {
        int q = tt;
        float z = 0.f;
        #pragma unroll
        for (int p = 0; p < 16; ++p) z += s_e[h][p][q];
        s_zi[h][q] = __builtin_amdgcn_rcpf(z);
    }
    __syncthreads();
    if (tt < 16) {
        int p = tt;
        float sw = 0.f;
        #pragma unroll
        for (int q = 0; q < 16; ++q) sw += s_e[h][p][q] * s_zi[h][q];
        s_w[h][p] = sw;
    }
    __syncthreads();
    if (tt < 64) {
        float acc = 0.f;
        #pragma unroll
        for (int p = 0; p < 16; ++p) acc += s_w[h][p] * s_xij[h][p][tt];
        xn[(size_t)node*64 + tt] = f2b(acc);
    }
}

extern "C" void kernel_launch(void* const* d_in, const int* in_sizes, int n_in,
                              void* d_out, int out_size, void* d_ws, size_t ws_size,
                              hipStream_t stream) {
    (void)in_sizes; (void)n_in; (void)out_size; (void)ws_size;
    const float* r    = (const float*)d_in[0];
    const int*   an   = (const int*)  d_in[1];
    const int*   src  = (const int*)  d_in[2];
    const float* emb  = (const float*)d_in[6];
    const float* Wsrc = (const float*)d_in[7];
    const float* bsrc = (const float*)d_in[8];
    const float* Wdst = (const float*)d_in[9];
    const float* bdst = (const float*)d_in[10];
    const float* Wedge= (const float*)d_in[11];
    const float* bedge= (const float*)d_in[12];
    const float* attn = (const float*)d_in[13];
    const float* W1   = (const float*)d_in[14];
    const float* b1   = (const float*)d_in[15];
    const float* W2   = (const float*)d_in[16];
    const float* b2   = (const float*)d_in[17];
    const float* Wfc  = (const float*)d_in[18];
    const float* bfc  = (const float*)d_in[19];

    char* ws = (char*)d_ws;
    float* d_d              = (float*)(ws);                    // 384000 B
    float* d_rhat           = (float*)(ws + 384000);           // 1536000 B
    unsigned short* wbf     = (unsigned short*)(ws + 1920000); // 2260992 B
    unsigned short* d_x     = (unsigned short*)(ws + 4180992); // 3072000 B
    unsigned short* d_xjxi  = (unsigned short*)(ws + 7252992); // 1536000 B
    unsigned short* d_eproj = (unsigned short*)(ws + 8788992); // 36864000 B
    unsigned short* d_xn    = (unsigned short*)(ws + 45652992);// 768000 B
    unsigned short* d_wcomb = (unsigned short*)(ws + 46420992);// 524288 B
    float* d_bcomb          = (float*)(ws + 46945280);         // 1024 B
    float* d_wfc2           = (float*)(ws + 46946304);         // 4096 B
    float* out = (float*)d_out;

    unsigned short* wsrc_bf  = wbf + WSRC_OFF;
    unsigned short* wdst_bf  = wbf + WDST_OFF;
    unsigned short* wedge_bf = wbf + WEDGE_OFF;
    unsigned short* w1_bf    = wbf + W1_OFF;

    prep_kernel<<<CVT4_BLOCKS + EMB4_BLOCKS + GEOM_BLOCKS + WCOMB_BLOCKS + WFC2_BLOCKS + 1,
                  256, 0, stream>>>(
        Wsrc, bsrc, Wdst, bdst, Wedge, W1, W2, b2, Wfc, bfc,
        wbf, an, emb, d_x, r, d_d, d_rhat, d_wcomb, d_bcomb, d_wfc2, out);

    // merged eproj + layer0 xj/xi GEMM (independent work, one dispatch)
    eplg_kernel<<<1500 + 188, 256, 0, stream>>>(
        wedge_bf, bedge, d_d, d_eproj,
        d_x, wsrc_bf, wdst_bf, bsrc, bdst, d_xjxi);

    // ---- layer 0 ----
    angle_kernel<<<N_NODES/2, 256, 0, stream>>>(
        d_xjxi, d_eproj, d_rhat, src, attn, d_xn);
    ffw_kernel<<<375, 256, 0, stream>>>(
        d_xn, w1_bf, b1, d_wcomb, d_bcomb, d_xjxi, N_NODES);

    // ---- layer 1 ----
    angle_kernel<<<N_NODES/2, 256, 0, stream>>>(
        d_xjxi, d_eproj + 64, d_rhat, src, attn + 64, d_xn);
    ffw_kernel<<<375, 256, 0, stream>>>(
        d_xn, w1_bf + 65536, b1 + 1024, d_wcomb + 131072, d_bcomb + 128, d_xjxi, N_NODES);

    // ---- layer 2 (FF fused with final reduction; no d_h, no reduce2) ----
    angle_kernel<<<N_NODES/2, 256, 0, stream>>>(
        d_xjxi, d_eproj + 128, d_rhat, src, attn + 128, d_xn);
    mgemm<2,0><<<dim3(16,94), 256, 0, stream>>>(
        d_xn, 64, w1_bf + 131072, (const unsigned short*)nullptr, 64,
        b1 + 2048, d_wfc2, (unsigned short*)out, 0, N_NODES, 64);
}

// Round 7
// 253.582 us; speedup vs baseline: 1.2335x; 1.1279x over previous
//
#include <hip/hip_runtime.h>

#define N_NODES 6000
#define DEG_    16
#define N_EDGES (N_NODES*DEG_)
#define D_MODEL 256
#define D_MSG   64
#define D_FF    1024

typedef __bf16 bf16x8 __attribute__((ext_vector_type(8)));
typedef float floatx4 __attribute__((ext_vector_type(4)));

__device__ __forceinline__ float silu_f(float v) {
    return v * __builtin_amdgcn_rcpf(1.0f + __expf(-v));
}
__device__ __forceinline__ float b2f(unsigned short u) {
    union { unsigned int i; float f; } v; v.i = ((unsigned int)u) << 16; return v.f;
}
__device__ __forceinline__ unsigned short f2b(float f) {
    union { float f; unsigned int i; } v; v.f = f;
    unsigned int r = (v.i + 0x7FFFu + ((v.i >> 16) & 1u)) >> 16;
    return (unsigned short)r;
}

// ---------------- fused prep: weight cvt + embed + geom + packed-weight precompute ----------------
// Fragment packing: packed[frag][lane]*8 ushorts, lane = lq*16+lr, so one wave-load of a
// B-fragment is 64 x 16B CONSECUTIVE (1KB coalesced) instead of 16B from 64 distinct lines.
#define WSRC_OFF 0
#define WDST_OFF 49152
#define WEDGE_OFF 98304
#define W1_OFF 147456
#define W2_OFF 344064
#define WTOTAL 1130496
#define CVT4_BLOCKS (WTOTAL/4/256)             // 1104
#define EMB4_BLOCKS (N_NODES*D_MODEL/4/256)    // 1500
#define GEOM_BLOCKS (N_EDGES/256)              // 375
#define WCOMB_BLOCKS 256                       // 2 layers x 128 rows (packed-layout output)
#define WFC2_BLOCKS 4
#define WPACKE_BLOCKS 24                       // Wedge pack: 6144 lane-frags (4w x 3ns x 8ks x 64)
#define WPACK1_BLOCKS 64                       // W1 pack (layers 0,1): 16384 lane-frags
__global__ __launch_bounds__(256) void prep_kernel(
    const float* __restrict__ Wsrc, const float* __restrict__ bsrc,
    const float* __restrict__ Wdst, const float* __restrict__ bdst,
    const float* __restrict__ Wedge, const float* __restrict__ W1,
    const float* __restrict__ W2, const float* __restrict__ b2,
    const float* __restrict__ Wfc, const float* __restrict__ bfc,
    unsigned short* __restrict__ wbf_out,
    const int* __restrict__ an, const float* __restrict__ emb,
    unsigned short* __restrict__ x,
    const float* __restrict__ r, float* __restrict__ d, float* __restrict__ rhat,
    unsigned short* __restrict__ wcomb,      // PACKED [2 layers][16384 frags][8]
    float* __restrict__ bcomb,
    float* __restrict__ wfc2,
    unsigned short* __restrict__ wedgep,     // PACKED [6144 frags][8]
    unsigned short* __restrict__ w1p,        // PACKED [2 layers][8192 frags][8]
    float* __restrict__ out) {
    int b = blockIdx.x;
    int t = threadIdx.x;
    if (b < CVT4_BLOCKS) {
        int i = (b*256 + t) * 4;
        const float* sp;
        if      (i < WDST_OFF)  sp = Wsrc + i;
        else if (i < WEDGE_OFF) sp = Wdst + (i - WDST_OFF);
        else if (i < W1_OFF)    sp = Wedge + (i - WEDGE_OFF);
        else if (i < W2_OFF)    sp = W1 + (i - W1_OFF);
        else                    sp = W2 + (i - W2_OFF);
        float4 v = *(const float4*)sp;
        *(ushort4*)(wbf_out + i) = make_ushort4(f2b(v.x), f2b(v.y), f2b(v.z), f2b(v.w));
    } else if (b < CVT4_BLOCKS + EMB4_BLOCKS) {
        int i4 = (b - CVT4_BLOCKS)*256 + t;
        int node = i4 >> 6, c4 = i4 & 63;
        float4 v = *(const float4*)(emb + (size_t)an[node]*D_MODEL + c4*4);
        *(ushort4*)(x + (size_t)node*D_MODEL + c4*4) =
            make_ushort4(f2b(v.x), f2b(v.y), f2b(v.z), f2b(v.w));
    } else if (b < CVT4_BLOCKS + EMB4_BLOCKS + GEOM_BLOCKS) {
        int e = (b - CVT4_BLOCKS - EMB4_BLOCKS)*256 + t;
        float xx = r[e*3+0], yy = r[e*3+1], zz = r[e*3+2];
        float n = sqrtf(xx*xx + yy*yy + zz*zz);
        d[e] = n;
        float inv = 1.0f / n;
        *(float4*)(rhat + (size_t)e*4) = make_float4(xx*inv, yy*inv, zz*inv, 0.f);
    } else if (b < CVT4_BLOCKS + EMB4_BLOCKS + GEOM_BLOCKS + WCOMB_BLOCKS) {
        int wb = b - (CVT4_BLOCKS + EMB4_BLOCKS + GEOM_BLOCKS);
        int lp  = 1 + (wb >> 7);
        int row = wb & 127;
        const float* wmrow = (row < 64) ? (Wsrc + (size_t)lp*16384 + row*256)
                                        : (Wdst + (size_t)lp*16384 + (row-64)*256);
        const float* W2f = W2 + (size_t)(lp-1)*262144;
        float a0 = 0.f, a1 = 0.f, a2 = 0.f, a3 = 0.f;
        int c0 = t*4;
        #pragma unroll 4
        for (int c = 0; c < 256; ++c) {
            float wm = wmrow[c];
            float4 w2v = *(const float4*)(W2f + (size_t)c*1024 + c0);
            a0 = fmaf(wm, w2v.x, a0);
            a1 = fmaf(wm, w2v.y, a1);
            a2 = fmaf(wm, w2v.z, a2);
            a3 = fmaf(wm, w2v.w, a3);
        }
        // store directly in PACKED fragment layout:
        // ushort off = fc*8192 + wv*2048 + ns*1024 + j*512 + lane*8 + cpos
        int fc = t >> 4, j = (t >> 3) & 1, lq = (t >> 1) & 3, cpos = (t & 1) * 4;
        int wv = row >> 5, ns = (row >> 4) & 1, lr = row & 15;
        int lane = lq*16 + lr;
        *(ushort4*)(wcomb + (size_t)(lp-1)*131072
                    + (size_t)fc*8192 + wv*2048 + ns*1024 + j*512 + lane*8 + cpos) =
            make_ushort4(f2b(a0), f2b(a1), f2b(a2), f2b(a3));
    } else if (b < CVT4_BLOCKS + EMB4_BLOCKS + GEOM_BLOCKS + WCOMB_BLOCKS + WFC2_BLOCKS) {
        int wb = b - (CVT4_BLOCKS + EMB4_BLOCKS + GEOM_BLOCKS + WCOMB_BLOCKS);
        int c = wb*256 + t;
        const float* W2f = W2 + 2*262144;
        float acc = 0.f;
        for (int k = 0; k < 256; ++k) acc += Wfc[k] * W2f[(size_t)k*1024 + c];
        wfc2[c] = acc;
    } else if (b < CVT4_BLOCKS + EMB4_BLOCKS + GEOM_BLOCKS + WCOMB_BLOCKS + WFC2_BLOCKS + WPACKE_BLOCKS) {
        // Wedge fragment pack: i = ((w*3+ns)*8+ks)*64 + lane, i in [0,6144)
        int wb = b - (CVT4_BLOCKS + EMB4_BLOCKS + GEOM_BLOCKS + WCOMB_BLOCKS + WFC2_BLOCKS);
        int i = wb*256 + t;                  // 0..6143
        int lane = i & 63, ks = (i >> 6) & 7, rem = i >> 9;   // rem 0..11
        int ns = rem % 3, w = rem / 3;                        // w 0..3
        int row = 48*w + ns*16 + (lane & 15);
        int col = ks*32 + (lane >> 4)*8;
        const float* sp = Wedge + (size_t)row*256 + col;
        float4 v0 = *(const float4*)sp;
        float4 v1 = *(const float4*)(sp + 4);
        unsigned short h[8] = { f2b(v0.x), f2b(v0.y), f2b(v0.z), f2b(v0.w),
                                f2b(v1.x), f2b(v1.y), f2b(v1.z), f2b(v1.w) };
        *(uint4*)(wedgep + (size_t)i*8) = *(uint4*)h;
    } else if (b < CVT4_BLOCKS + EMB4_BLOCKS + GEOM_BLOCKS + WCOMB_BLOCKS + WFC2_BLOCKS + WPACKE_BLOCKS + WPACK1_BLOCKS) {
        // W1 fragment pack (layers 0,1): i2 = lp*8192 + f*512 + wv*128 + j*64 + lane
        int wb = b - (CVT4_BLOCKS + EMB4_BLOCKS + GEOM_BLOCKS + WCOMB_BLOCKS + WFC2_BLOCKS + WPACKE_BLOCKS);
        int i2 = wb*256 + t;                 // 0..16383
        int lp = i2 >> 13;
        int e = i2 & 8191;
        int lane = e & 63, j = (e >> 6) & 1, wv = (e >> 7) & 3, f = e >> 9;
        int row = f*64 + wv*16 + (lane & 15);
        int col = j*32 + (lane >> 4)*8;
        const float* sp = W1 + (size_t)lp*65536 + (size_t)row*64 + col;
        float4 v0 = *(const float4*)sp;
        float4 v1 = *(const float4*)(sp + 4);
        unsigned short h[8] = { f2b(v0.x), f2b(v0.y), f2b(v0.z), f2b(v0.w),
                                f2b(v1.x), f2b(v1.y), f2b(v1.z), f2b(v1.w) };
        *(uint4*)(w1p + (size_t)i2*8) = *(uint4*)h;
    } else {
        int lp = 1 + (t >> 7);
        int row = t & 127;
        const float* b2l = b2 + (lp-1)*256;
        const float* wmrow = (row < 64) ? (Wsrc + (size_t)lp*16384 + row*256)
                                        : (Wdst + (size_t)lp*16384 + (row-64)*256);
        float acc = 0.f;
        for (int c = 0; c < 256; ++c) acc += wmrow[c] * b2l[c];
        acc += (row < 64) ? bsrc[lp*64 + row] : bdst[lp*64 + (row-64)];
        bcomb[(lp-1)*128 + row] = acc;
        if (t == 0) {
            float bo = 0.f;
            const float* b23 = b2 + 2*256;
            for (int c = 0; c < 256; ++c) bo += Wfc[c] * b23[c];
            out[0] = bo + bfc[0];
        }
    }
}

// ---------------- merged eproj + layer0 xj/xi GEMM ----------------
// eproj B reads PACKED Wedge fragments: 1KB coalesced per wave-load, identical
// address stream across all 1500 blocks (L1/L2 broadcast).
#define EPITCH 264
#define APITCH 40
#define MCP 72
__global__ __launch_bounds__(256) void eplg_kernel(
    const unsigned short* __restrict__ Bwp,  // PACKED Wedge frags
    const float* __restrict__ bias,          // bedge [192]
    const float* __restrict__ dvec,          // [E]
    unsigned short* __restrict__ C,          // eproj out [E,192]
    const unsigned short* __restrict__ A,    // d_x [N,256]
    const unsigned short* __restrict__ B1g,  // wsrc [64,256]
    const unsigned short* __restrict__ B2g,  // wdst [64,256]
    const float* __restrict__ bias1,         // bsrc
    const float* __restrict__ bias2,         // bdst
    unsigned short* __restrict__ Cg) {       // d_xjxi [N,128]
    __shared__ __align__(16) unsigned short sm[64*EPITCH];   // 33792 B (union)
    const int t = threadIdx.x;
    const int w = t >> 6, lane = t & 63, lr = lane & 15, lq = lane >> 4;

    if (blockIdx.x < 1500) {
        // ================= eproj =================
        unsigned short* As = sm;
        const int m0 = blockIdx.x * 64;
        const int arow = t >> 2, achk = t & 3;

        float dv = dvec[m0 + arow];
        const float gamma = 31.875f;
        const float step  = 8.0f / 255.0f;
        #pragma unroll
        for (int c32 = 0; c32 < 8; ++c32) {
            int kb = c32*32 + achk*8;
            unsigned short h[8];
            #pragma unroll
            for (int j = 0; j < 8; ++j) {
                float tt = dv - (float)(kb+j)*step;
                h[j] = f2b(__expf(-gamma*tt*tt));
            }
            *(uint4*)(&As[arow*EPITCH + kb]) = *(uint4*)h;
        }
        __syncthreads();

        // packed fragment base for this (wave, lane)
        const unsigned short* Bp = Bwp + (size_t)w*12288 + lane*8;

        floatx4 acc[4][3] = {};
        uint4 pb[3];
        #pragma unroll
        for (int ns = 0; ns < 3; ++ns)
            pb[ns] = *(const uint4*)(Bp + ns*4096);

        for (int k0 = 0; k0 < 256; k0 += 32) {
            int ks = k0 >> 5;
            uint4 cb[3];
            cb[0] = pb[0]; cb[1] = pb[1]; cb[2] = pb[2];
            if (k0 + 32 < 256) {
                #pragma unroll
                for (int ns = 0; ns < 3; ++ns)
                    pb[ns] = *(const uint4*)(Bp + ns*4096 + (ks+1)*512);
            }
            bf16x8 af[4];
            #pragma unroll
            for (int mi = 0; mi < 4; ++mi)
                af[mi] = *(const bf16x8*)(&As[(mi*16 + lr)*EPITCH + k0 + lq*8]);
            #pragma unroll
            for (int mi = 0; mi < 4; ++mi) {
                #pragma unroll
                for (int ns = 0; ns < 3; ++ns)
                    acc[mi][ns] = __builtin_amdgcn_mfma_f32_16x16x32_bf16(
                        af[mi], *(const bf16x8*)&cb[ns], acc[mi][ns], 0, 0, 0);
            }
        }

        #pragma unroll
        for (int ns = 0; ns < 3; ++ns) {
            int bc = 48*w + ns*16 + lr;
            float bv = bias[bc];
            #pragma unroll
            for (int mi = 0; mi < 4; ++mi) {
                #pragma unroll
                for (int rg = 0; rg < 4; ++rg) {
                    int row = m0 + mi*16 + lq*4 + rg;
                    C[(size_t)row*192 + bc] = f2b(acc[mi][ns][rg] + bv);
                }
            }
        }
        return;
    }
    // ================= layer0 dual-B GEMM (K=256, M=6000) =================
    {
        unsigned short* As = sm;          // 64*40
        unsigned short* Bs = sm + 2560;   // 64*40
        unsigned short* Cs = sm;          // 64*72 epilogue reuse
        const int bid2 = blockIdx.x - 1500;
        const int bx = bid2 & 1;
        const int m0 = (bid2 >> 1) * 64;
        const unsigned short* B = bx ? B2g : B1g;
        const float* biasl = bx ? bias2 : bias1;
        const int n0 = bx * 64;
        const int K = 256, M = N_NODES, lda = 256, ldb = 256, ldc = 128;

        const int arow = t >> 2, achk = t & 3;

        floatx4 acc[4] = {};
        uint4 pa, pb;
        {
            int gm = m0 + arow;
            pa = (gm < M) ? *(const uint4*)(A + (size_t)gm*lda + achk*8) : make_uint4(0,0,0,0);
        }
        pb = *(const uint4*)(B + (size_t)arow*ldb + achk*8);

        for (int k0 = 0; k0 < K; k0 += 32) {
            *(uint4*)(&As[arow*APITCH + achk*8]) = pa;
            *(uint4*)(&Bs[arow*APITCH + achk*8]) = pb;
            __syncthreads();
            if (k0 + 32 < K) {
                int kn = k0 + 32;
                int gm = m0 + arow;
                pa = (gm < M) ? *(const uint4*)(A + (size_t)gm*lda + kn + achk*8) : make_uint4(0,0,0,0);
                pb = *(const uint4*)(B + (size_t)arow*ldb + kn + achk*8);
            }
            bf16x8 af, bfr[4];
            af = *(const bf16x8*)(&As[(w*16 + lr)*APITCH + lq*8]);
            #pragma unroll
            for (int ns = 0; ns < 4; ++ns)
                bfr[ns] = *(const bf16x8*)(&Bs[(ns*16 + lr)*APITCH + lq*8]);
            #pragma unroll
            for (int ns = 0; ns < 4; ++ns)
                acc[ns] = __builtin_amdgcn_mfma_f32_16x16x32_bf16(af, bfr[ns], acc[ns], 0,0,0);
            __syncthreads();
        }
        #pragma unroll
        for (int ns = 0; ns < 4; ++ns) {
            int bc = ns*16 + lr;
            float bv = biasl[bc];
            #pragma unroll
            for (int rg = 0; rg < 4; ++rg) {
                int lrow = w*16 + lq*4 + rg;
                Cs[lrow*MCP + bc] = f2b(acc[ns][rg] + bv);
            }
        }
        __syncthreads();
        #pragma unroll
        for (int it = 0; it < 2; ++it) {
            int i = t + it*256;
            int row = i >> 3, c8 = i & 7;
            int gm = m0 + row;
            if (gm < M)
                *(uint4*)(Cg + (size_t)gm*ldc + n0 + c8*8) = *(const uint4*)(Cs + row*MCP + c8*8);
        }
    }
}

// ---------------- MFMA bf16 GEMM (LDS version; layer-2 FF + fused final reduction) ----------------
template<int ACT, int DUALB>
__global__ __launch_bounds__(256) void mgemm(
    const unsigned short* __restrict__ A, int lda,
    const unsigned short* __restrict__ B1, const unsigned short* __restrict__ B2, int ldb,
    const float* __restrict__ bias1, const float* __restrict__ bias2,
    unsigned short* __restrict__ C, int ldc, int M, int K) {
    __shared__ __align__(16) unsigned short sm[5120];
    unsigned short* As = sm;
    unsigned short* Bs = sm + 2560;
    unsigned short* Cs = sm;
    const int t = threadIdx.x;
    const int w = t >> 6;
    const int lane = t & 63;
    const int lr = lane & 15;
    const int lq = lane >> 4;
    const int n0 = blockIdx.x * 64;
    const int m0 = blockIdx.y * 64;
    const unsigned short* B = B1;
    const float* bias = bias1;
    if (DUALB && blockIdx.x == 1) { B = B2; bias = bias2; }
    const unsigned short* Brow = DUALB ? B : (B + (size_t)n0*ldb);

    const int arow = t >> 2, achk = t & 3;

    floatx4 acc[4] = {};
    uint4 pa, pb;
    {
        int gm = m0 + arow;
        pa = (gm < M) ? *(const uint4*)(A + (size_t)gm*lda + achk*8) : make_uint4(0,0,0,0);
    }
    pb = *(const uint4*)(Brow + (size_t)arow*ldb + achk*8);

    for (int k0 = 0; k0 < K; k0 += 32) {
        *(uint4*)(&As[arow*APITCH + achk*8]) = pa;
        *(uint4*)(&Bs[arow*APITCH + achk*8]) = pb;
        __syncthreads();
        if (k0 + 32 < K) {
            int kn = k0 + 32;
            int gm = m0 + arow;
            pa = (gm < M) ? *(const uint4*)(A + (size_t)gm*lda + kn + achk*8) : make_uint4(0,0,0,0);
            pb = *(const uint4*)(Brow + (size_t)arow*ldb + kn + achk*8);
        }
        bf16x8 af, bfr[4];
        af = *(const bf16x8*)(&As[(w*16 + lr)*APITCH + lq*8]);
        #pragma unroll
        for (int ns = 0; ns < 4; ++ns)
            bfr[ns] = *(const bf16x8*)(&Bs[(ns*16 + lr)*APITCH + lq*8]);
        #pragma unroll
        for (int ns = 0; ns < 4; ++ns)
            acc[ns] = __builtin_amdgcn_mfma_f32_16x16x32_bf16(af, bfr[ns], acc[ns], 0,0,0);
        __syncthreads();
    }
    if (ACT == 2) {
        float partial = 0.f;
        #pragma unroll
        for (int ns = 0; ns < 4; ++ns) {
            int bc = ns*16 + lr;
            float bv = bias[n0 + bc];
            float wv = bias2[n0 + bc];
            #pragma unroll
            for (int rg = 0; rg < 4; ++rg) {
                int gm = m0 + w*16 + lq*4 + rg;
                float v = silu_f(acc[ns][rg] + bv);
                if (gm < M) partial += v * wv;
            }
        }
        float* red = (float*)sm;
        red[t] = partial;
        __syncthreads();
        for (int off = 128; off > 0; off >>= 1) {
            if (t < off) red[t] += red[t+off];
            __syncthreads();
        }
        if (t == 0) atomicAdd((float*)C, red[0] * (1.0f/(float)N_NODES));
        return;
    }
    #pragma unroll
    for (int ns = 0; ns < 4; ++ns) {
        int bc = ns*16 + lr;
        float bv = bias[DUALB ? bc : (n0 + bc)];
        #pragma unroll
        for (int rg = 0; rg < 4; ++rg) {
            int lrow = w*16 + lq*4 + rg;
            float v = acc[ns][rg] + bv;
            if (ACT) v = silu_f(v);
            Cs[lrow*MCP + bc] = f2b(v);
        }
    }
    __syncthreads();
    #pragma unroll
    for (int it = 0; it < 2; ++it) {
        int i = t + it*256;
        int row = i >> 3, c8 = i & 7;
        int gm = m0 + row;
        if (gm < M)
            *(uint4*)(C + (size_t)gm*ldc + n0 + c8*8) = *(const uint4*)(Cs + row*MCP + c8*8);
    }
}

// ---------------- fused FF + wcomb with PACKED weight fragments ----------------
#define HP 72
#define CP2 136
__global__ __launch_bounds__(256) void ffw_kernel(
    const unsigned short* __restrict__ XN,   // [N,64] bf16
    const unsigned short* __restrict__ W1p,  // PACKED W1 frags (this layer)
    const float* __restrict__ b1l,           // [1024]
    const unsigned short* __restrict__ WCp,  // PACKED wcomb frags (this layer)
    const float* __restrict__ bcl,           // [128]
    unsigned short* __restrict__ XO,         // [N,128] bf16
    int M) {
    __shared__ __align__(16) unsigned short s_h[16*HP];    // h chunk [16][72]
    __shared__ __align__(16) unsigned short s_c[16*CP2];   // epilogue [16][136]
    const int t = threadIdx.x;
    const int wv = t >> 6, lane = t & 63, lr = lane & 15, lq = lane >> 4;
    const int m0 = blockIdx.x * 16;

    int ga = m0 + lr;
    bool aok = ga < M;
    uint4 a0 = aok ? *(const uint4*)(XN + (size_t)ga*64 + lq*8) : make_uint4(0,0,0,0);
    uint4 a1 = aok ? *(const uint4*)(XN + (size_t)ga*64 + 32 + lq*8) : make_uint4(0,0,0,0);

    floatx4 acc2[2] = {};

    // packed fragment bases for this (wave, lane): loads are 1KB coalesced per wave
    const unsigned short* W1b = W1p + (size_t)wv*1024 + lane*8;   // + f*4096 + j*512
    const unsigned short* WCb = WCp + (size_t)wv*2048 + lane*8;   // + f*8192 + ns*1024 + j*512

    uint4 pb1[2], pb2[4];
    pb1[0] = *(const uint4*)(W1b);
    pb1[1] = *(const uint4*)(W1b + 512);
    pb2[0] = *(const uint4*)(WCb);
    pb2[1] = *(const uint4*)(WCb + 512);
    pb2[2] = *(const uint4*)(WCb + 1024);
    pb2[3] = *(const uint4*)(WCb + 1536);

    for (int f = 0; f < 16; ++f) {
        uint4 cb1_0 = pb1[0], cb1_1 = pb1[1];
        uint4 cb2_0 = pb2[0], cb2_1 = pb2[1], cb2_2 = pb2[2], cb2_3 = pb2[3];
        float bv1 = b1l[f*64 + wv*16 + lr];
        if (f < 15) {
            const unsigned short* n1 = W1b + (f+1)*4096;
            const unsigned short* n2 = WCb + (f+1)*8192;
            pb1[0] = *(const uint4*)(n1);
            pb1[1] = *(const uint4*)(n1 + 512);
            pb2[0] = *(const uint4*)(n2);
            pb2[1] = *(const uint4*)(n2 + 512);
            pb2[2] = *(const uint4*)(n2 + 1024);
            pb2[3] = *(const uint4*)(n2 + 1536);
        }
        // ---- first GEMM: h chunk [16 nodes x 64 ff], wave wv owns 16 ff-cols ----
        floatx4 hacc = {};
        hacc = __builtin_amdgcn_mfma_f32_16x16x32_bf16(
            *(const bf16x8*)&a0, *(const bf16x8*)&cb1_0, hacc, 0,0,0);
        hacc = __builtin_amdgcn_mfma_f32_16x16x32_bf16(
            *(const bf16x8*)&a1, *(const bf16x8*)&cb1_1, hacc, 0,0,0);
        {
            int col = wv*16 + lr;
            #pragma unroll
            for (int rg = 0; rg < 4; ++rg) {
                int row = lq*4 + rg;
                s_h[row*HP + col] = f2b(silu_f(hacc[rg] + bv1));
            }
        }
        __syncthreads();
        // ---- second GEMM: acc2 += h_chunk @ wcomb_chunk^T, wave wv owns 32 out-cols ----
        bf16x8 ha0 = *(const bf16x8*)(&s_h[lr*HP + lq*8]);
        bf16x8 ha1 = *(const bf16x8*)(&s_h[lr*HP + 32 + lq*8]);
        acc2[0] = __builtin_amdgcn_mfma_f32_16x16x32_bf16(ha0, *(const bf16x8*)&cb2_0, acc2[0], 0,0,0);
        acc2[0] = __builtin_amdgcn_mfma_f32_16x16x32_bf16(ha1, *(const bf16x8*)&cb2_1, acc2[0], 0,0,0);
        acc2[1] = __builtin_amdgcn_mfma_f32_16x16x32_bf16(ha0, *(const bf16x8*)&cb2_2, acc2[1], 0,0,0);
        acc2[1] = __builtin_amdgcn_mfma_f32_16x16x32_bf16(ha1, *(const bf16x8*)&cb2_3, acc2[1], 0,0,0);
        __syncthreads();
    }

    #pragma unroll
    for (int ns = 0; ns < 2; ++ns) {
        int col = wv*32 + ns*16 + lr;
        float bv = bcl[col];
        #pragma unroll
        for (int rg = 0; rg < 4; ++rg) {
            int row = lq*4 + rg;
            s_c[row*CP2 + col] = f2b(acc2[ns][rg] + bv);
        }
    }
    __syncthreads();
    {
        int row = t >> 4, c8 = t & 15;
        int gm = m0 + row;
        if (gm < M)
            *(uint4*)(XO + (size_t)gm*128 + c8*8) = *(const uint4*)(s_c + row*CP2 + c8*8);
    }
}

// ---------------- angle attention, TWO nodes per block ----------------
__global__ __launch_bounds__(256) void angle_kernel(
    const unsigned short* __restrict__ xjxi,
    const unsigned short* __restrict__ eproj,
    const float* __restrict__ rhat,
    const int*   __restrict__ src,
    const float* __restrict__ attn,
    unsigned short* __restrict__ xn) {
    __shared__ __align__(16) float s_xij[2][16][68];
    __shared__ float s_rhat[2][16][4];
    __shared__ float s_logit[2][16][17];
    __shared__ float s_e[2][16][17];
    __shared__ float s_m[2][16], s_zi[2][16];
    __shared__ float s_w[2][16];
    const int t = threadIdx.x;
    const int h = t >> 7, tt = t & 127;
    const int node = blockIdx.x*2 + h;

    if (tt < 16) {
        float4 rv = *(const float4*)(rhat + (size_t)(node*DEG_ + tt)*4);
        s_rhat[h][tt][0] = rv.x; s_rhat[h][tt][1] = rv.y; s_rhat[h][tt][2] = rv.z; s_rhat[h][tt][3] = 0.f;
        s_e[h][tt][tt] = 0.f;
    }
    {
        int p = tt >> 3, c8 = tt & 7;
        int e = node*DEG_ + p;
        int se = src[e];
        uint4 aj = *(const uint4*)(xjxi + (size_t)se*128 + c8*8);
        uint4 ai = *(const uint4*)(xjxi + (size_t)node*128 + 64 + c8*8);
        uint4 ae = *(const uint4*)(eproj + (size_t)e*192 + c8*8);
        const unsigned short* pj = (const unsigned short*)&aj;
        const unsigned short* pi = (const unsigned short*)&ai;
        const unsigned short* pe = (const unsigned short*)&ae;
        #pragma unroll
        for (int j = 0; j < 8; ++j)
            s_xij[h][p][c8*8 + j] = b2f(pj[j]) + b2f(pi[j]) + b2f(pe[j]);
    }
    __syncthreads();
    int pp = 0, qq = 0;
    float lg = 0.f;
    if (tt < 120) {
        pp = (int)((1.0f + sqrtf(8.0f*(float)tt + 1.0f)) * 0.5f);
        qq = tt - ((pp*(pp-1)) >> 1);
        float c = s_rhat[h][pp][0]*s_rhat[h][qq][0] + s_rhat[h][pp][1]*s_rhat[h][qq][1]
                + s_rhat[h][pp][2]*s_rhat[h][qq][2];
        c = fminf(fmaxf(c, -0.999999f), 0.999999f);
        float c2  = 2.0f * c;
        float tk0 = 1.0f;
        float tk1 = c;
        float acc = 0.f;
        const float* xp = &s_xij[h][pp][0];
        const float* xq = &s_xij[h][qq][0];
        #pragma unroll
        for (int k0 = 0; k0 < 64; k0 += 4) {
            float4 xp4 = *(const float4*)(xp + k0);
            float4 xq4 = *(const float4*)(xq + k0);
            float a0 = attn[k0+0], a1 = attn[k0+1], a2 = attn[k0+2], a3 = attn[k0+3];
            float v0 = tk0 + xp4.x + xq4.x;
            acc = fmaf(a0, silu_f(v0), acc);
            { float tn2 = c2*tk1 - tk0; tk0 = tk1; tk1 = tn2; }
            float v1 = tk0 + xp4.y + xq4.y;
            acc = fmaf(a1, silu_f(v1), acc);
            { float tn2 = c2*tk1 - tk0; tk0 = tk1; tk1 = tn2; }
            float v2 = tk0 + xp4.z + xq4.z;
            acc = fmaf(a2, silu_f(v2), acc);
            { float tn2 = c2*tk1 - tk0; tk0 = tk1; tk1 = tn2; }
            float v3 = tk0 + xp4.w + xq4.w;
            acc = fmaf(a3, silu_f(v3), acc);
            { float tn2 = c2*tk1 - tk0; tk0 = tk1; tk1 = tn2; }
        }
        lg = acc;
        s_logit[h][pp][qq] = acc;
        s_logit[h][qq][pp] = acc;
    }
    __syncthreads();
    if (tt < 16) {
        int q = tt;
        float mx = -1e30f;
        #pragma unroll
        for (int p = 0; p < 16; ++p) if (p != q) mx = fmaxf(mx, s_logit[h][p][q]);
        s_m[h][q] = mx;
    }
    __syncthreads();
    if (tt < 120) {
        s_e[h][pp][qq] = __expf(lg - s_m[h][qq]);
        s_e[h][qq][pp] = __expf(lg - s_m[h][pp]);
    }
    __syncthreads();
    if (tt < 16) {
        int q = tt;
        float z = 0.f;
        #pragma unroll
        for (int p = 0; p < 16; ++p) z += s_e[h][p][q];
        s_zi[h][q] = __builtin_amdgcn_rcpf(z);
    }
    __syncthreads();
    if (tt < 16) {
        int p = tt;
        float sw = 0.f;
        #pragma unroll
        for (int q = 0; q < 16; ++q) sw += s_e[h][p][q] * s_zi[h][q];
        s_w[h][p] = sw;
    }
    __syncthreads();
    if (tt < 64) {
        float acc = 0.f;
        #pragma unroll
        for (int p = 0; p < 16; ++p) acc += s_w[h][p] * s_xij[h][p][tt];
        xn[(size_t)node*64 + tt] = f2b(acc);
    }
}

extern "C" void kernel_launch(void* const* d_in, const int* in_sizes, int n_in,
                              void* d_out, int out_size, void* d_ws, size_t ws_size,
                              hipStream_t stream) {
    (void)in_sizes; (void)n_in; (void)out_size; (void)ws_size;
    const float* r    = (const float*)d_in[0];
    const int*   an   = (const int*)  d_in[1];
    const int*   src  = (const int*)  d_in[2];
    const float* emb  = (const float*)d_in[6];
    const float* Wsrc = (const float*)d_in[7];
    const float* bsrc = (const float*)d_in[8];
    const float* Wdst = (const float*)d_in[9];
    const float* bdst = (const float*)d_in[10];
    const float* Wedge= (const float*)d_in[11];
    const float* bedge= (const float*)d_in[12];
    const float* attn = (const float*)d_in[13];
    const float* W1   = (const float*)d_in[14];
    const float* b1   = (const float*)d_in[15];
    const float* W2   = (const float*)d_in[16];
    const float* b2   = (const float*)d_in[17];
    const float* Wfc  = (const float*)d_in[18];
    const float* bfc  = (const float*)d_in[19];

    char* ws = (char*)d_ws;
    float* d_d              = (float*)(ws);                    // 384000 B
    float* d_rhat           = (float*)(ws + 384000);           // 1536000 B
    unsigned short* wbf     = (unsigned short*)(ws + 1920000); // 2260992 B
    unsigned short* d_x     = (unsigned short*)(ws + 4180992); // 3072000 B
    unsigned short* d_xjxi  = (unsigned short*)(ws + 7252992); // 1536000 B
    unsigned short* d_eproj = (unsigned short*)(ws + 8788992); // 36864000 B
    unsigned short* d_xn    = (unsigned short*)(ws + 45652992);// 768000 B
    unsigned short* d_wcomb = (unsigned short*)(ws + 46420992);// 524288 B (packed)
    float* d_bcomb          = (float*)(ws + 46945280);         // 1024 B
    float* d_wfc2           = (float*)(ws + 46946304);         // 4096 B
    unsigned short* d_wedgep= (unsigned short*)(ws + 46950400);// 98304 B (packed)
    unsigned short* d_w1p   = (unsigned short*)(ws + 47048704);// 262144 B (packed, 2 layers)
    float* out = (float*)d_out;

    unsigned short* wsrc_bf  = wbf + WSRC_OFF;
    unsigned short* wdst_bf  = wbf + WDST_OFF;
    unsigned short* w1_bf    = wbf + W1_OFF;

    prep_kernel<<<CVT4_BLOCKS + EMB4_BLOCKS + GEOM_BLOCKS + WCOMB_BLOCKS + WFC2_BLOCKS
                  + WPACKE_BLOCKS + WPACK1_BLOCKS + 1, 256, 0, stream>>>(
        Wsrc, bsrc, Wdst, bdst, Wedge, W1, W2, b2, Wfc, bfc,
        wbf, an, emb, d_x, r, d_d, d_rhat, d_wcomb, d_bcomb, d_wfc2,
        d_wedgep, d_w1p, out);

    // merged eproj (packed Wedge) + layer0 xj/xi GEMM
    eplg_kernel<<<1500 + 188, 256, 0, stream>>>(
        d_wedgep, bedge, d_d, d_eproj,
        d_x, wsrc_bf, wdst_bf, bsrc, bdst, d_xjxi);

    // ---- layer 0 ----
    angle_kernel<<<N_NODES/2, 256, 0, stream>>>(
        d_xjxi, d_eproj, d_rhat, src, attn, d_xn);
    ffw_kernel<<<375, 256, 0, stream>>>(
        d_xn, d_w1p, b1, d_wcomb, d_bcomb, d_xjxi, N_NODES);

    // ---- layer 1 ----
    angle_kernel<<<N_NODES/2, 256, 0, stream>>>(
        d_xjxi, d_eproj + 64, d_rhat, src, attn + 64, d_xn);
    ffw_kernel<<<375, 256, 0, stream>>>(
        d_xn, d_w1p + 65536, b1 + 1024, d_wcomb + 131072, d_bcomb + 128, d_xjxi, N_NODES);

    // ---- layer 2 (FF fused with final reduction; no d_h, no reduce2) ----
    angle_kernel<<<N_NODES/2, 256, 0, stream>>>(
        d_xjxi, d_eproj + 128, d_rhat, src, attn + 128, d_xn);
    mgemm<2,0><<<dim3(16,94), 256, 0, stream>>>(
        d_xn, 64, w1_bf + 131072, (const unsigned short*)nullptr, 64,
        b1 + 2048, d_wfc2, (unsigned short*)out, 0, N_NODES, 64);
}

// Round 8
// 251.335 us; speedup vs baseline: 1.2446x; 1.0089x over previous
//
#include <hip/hip_runtime.h>

#define N_NODES 6000
#define DEG_    16
#define N_EDGES (N_NODES*DEG_)
#define D_MODEL 256
#define D_MSG   64
#define D_FF    1024

typedef __bf16 bf16x8 __attribute__((ext_vector_type(8)));
typedef float floatx4 __attribute__((ext_vector_type(4)));

__device__ __forceinline__ float silu_f(float v) {
    return v * __builtin_amdgcn_rcpf(1.0f + __expf(-v));
}
__device__ __forceinline__ float b2f(unsigned short u) {
    union { unsigned int i; float f; } v; v.i = ((unsigned int)u) << 16; return v.f;
}
__device__ __forceinline__ unsigned short f2b(float f) {
    union { float f; unsigned int i; } v; v.f = f;
    unsigned int r = (v.i + 0x7FFFu + ((v.i >> 16) & 1u)) >> 16;
    return (unsigned short)r;
}

// ---------------- fused prep: weight cvt + embed + geom + packed-weight precompute ----------------
// Fragment packing: packed[frag][lane]*8 ushorts, lane = lq*16+lr, so one wave-load of a
// B-fragment is 64 x 16B CONSECUTIVE (1KB coalesced) instead of 16B from 64 distinct lines.
#define WSRC_OFF 0
#define WDST_OFF 49152
#define WCVT_TOTAL 98304                       // only wsrc/wdst need bf16 row-major copies
#define CVT4_BLOCKS (WCVT_TOTAL/4/256)         // 96
#define EMB4_BLOCKS (N_NODES*D_MODEL/4/256)    // 1500
#define GEOM_BLOCKS (N_EDGES/256)              // 375
#define WCOMB_BLOCKS 256                       // 2 layers x 128 rows (packed-layout output)
#define WFC2_BLOCKS 4
#define WPACKE_BLOCKS 24                       // Wedge pack: 6144 lane-frags (4w x 3ns x 8ks x 64)
#define WPACK1_BLOCKS 96                       // W1 pack (3 layers): 24576 lane-frags
__global__ __launch_bounds__(256) void prep_kernel(
    const float* __restrict__ Wsrc, const float* __restrict__ bsrc,
    const float* __restrict__ Wdst, const float* __restrict__ bdst,
    const float* __restrict__ Wedge, const float* __restrict__ W1,
    const float* __restrict__ W2, const float* __restrict__ b2,
    const float* __restrict__ Wfc, const float* __restrict__ bfc,
    unsigned short* __restrict__ wbf_out,
    const int* __restrict__ an, const float* __restrict__ emb,
    unsigned short* __restrict__ x,
    const float* __restrict__ r, float* __restrict__ d, float* __restrict__ rhat,
    unsigned short* __restrict__ wcomb,      // PACKED [2 layers][16384 frags][8]
    float* __restrict__ bcomb,
    float* __restrict__ wfc2,
    unsigned short* __restrict__ wedgep,     // PACKED [6144 frags][8]
    unsigned short* __restrict__ w1p,        // PACKED [3 layers][8192 frags][8]
    float* __restrict__ out) {
    int b = blockIdx.x;
    int t = threadIdx.x;
    if (b < CVT4_BLOCKS) {
        int i = (b*256 + t) * 4;
        const float* sp = (i < WDST_OFF) ? (Wsrc + i) : (Wdst + (i - WDST_OFF));
        float4 v = *(const float4*)sp;
        *(ushort4*)(wbf_out + i) = make_ushort4(f2b(v.x), f2b(v.y), f2b(v.z), f2b(v.w));
    } else if (b < CVT4_BLOCKS + EMB4_BLOCKS) {
        int i4 = (b - CVT4_BLOCKS)*256 + t;
        int node = i4 >> 6, c4 = i4 & 63;
        float4 v = *(const float4*)(emb + (size_t)an[node]*D_MODEL + c4*4);
        *(ushort4*)(x + (size_t)node*D_MODEL + c4*4) =
            make_ushort4(f2b(v.x), f2b(v.y), f2b(v.z), f2b(v.w));
    } else if (b < CVT4_BLOCKS + EMB4_BLOCKS + GEOM_BLOCKS) {
        int e = (b - CVT4_BLOCKS - EMB4_BLOCKS)*256 + t;
        float xx = r[e*3+0], yy = r[e*3+1], zz = r[e*3+2];
        float n = sqrtf(xx*xx + yy*yy + zz*zz);
        d[e] = n;
        float inv = 1.0f / n;
        *(float4*)(rhat + (size_t)e*4) = make_float4(xx*inv, yy*inv, zz*inv, 0.f);
    } else if (b < CVT4_BLOCKS + EMB4_BLOCKS + GEOM_BLOCKS + WCOMB_BLOCKS) {
        int wb = b - (CVT4_BLOCKS + EMB4_BLOCKS + GEOM_BLOCKS);
        int lp  = 1 + (wb >> 7);
        int row = wb & 127;
        const float* wmrow = (row < 64) ? (Wsrc + (size_t)lp*16384 + row*256)
                                        : (Wdst + (size_t)lp*16384 + (row-64)*256);
        const float* W2f = W2 + (size_t)(lp-1)*262144;
        float a0 = 0.f, a1 = 0.f, a2 = 0.f, a3 = 0.f;
        int c0 = t*4;
        #pragma unroll 4
        for (int c = 0; c < 256; ++c) {
            float wm = wmrow[c];
            float4 w2v = *(const float4*)(W2f + (size_t)c*1024 + c0);
            a0 = fmaf(wm, w2v.x, a0);
            a1 = fmaf(wm, w2v.y, a1);
            a2 = fmaf(wm, w2v.z, a2);
            a3 = fmaf(wm, w2v.w, a3);
        }
        // store directly in PACKED fragment layout:
        // ushort off = fc*8192 + wv*2048 + ns*1024 + j*512 + lane*8 + cpos
        int fc = t >> 4, j = (t >> 3) & 1, lq = (t >> 1) & 3, cpos = (t & 1) * 4;
        int wv = row >> 5, ns = (row >> 4) & 1, lr = row & 15;
        int lane = lq*16 + lr;
        *(ushort4*)(wcomb + (size_t)(lp-1)*131072
                    + (size_t)fc*8192 + wv*2048 + ns*1024 + j*512 + lane*8 + cpos) =
            make_ushort4(f2b(a0), f2b(a1), f2b(a2), f2b(a3));
    } else if (b < CVT4_BLOCKS + EMB4_BLOCKS + GEOM_BLOCKS + WCOMB_BLOCKS + WFC2_BLOCKS) {
        int wb = b - (CVT4_BLOCKS + EMB4_BLOCKS + GEOM_BLOCKS + WCOMB_BLOCKS);
        int c = wb*256 + t;
        const float* W2f = W2 + 2*262144;
        float acc = 0.f;
        for (int k = 0; k < 256; ++k) acc += Wfc[k] * W2f[(size_t)k*1024 + c];
        wfc2[c] = acc;
    } else if (b < CVT4_BLOCKS + EMB4_BLOCKS + GEOM_BLOCKS + WCOMB_BLOCKS + WFC2_BLOCKS + WPACKE_BLOCKS) {
        // Wedge fragment pack: i = ((w*3+ns)*8+ks)*64 + lane, i in [0,6144)
        int wb = b - (CVT4_BLOCKS + EMB4_BLOCKS + GEOM_BLOCKS + WCOMB_BLOCKS + WFC2_BLOCKS);
        int i = wb*256 + t;                  // 0..6143
        int lane = i & 63, ks = (i >> 6) & 7, rem = i >> 9;   // rem 0..11
        int ns = rem % 3, w = rem / 3;                        // w 0..3
        int row = 48*w + ns*16 + (lane & 15);
        int col = ks*32 + (lane >> 4)*8;
        const float* sp = Wedge + (size_t)row*256 + col;
        float4 v0 = *(const float4*)sp;
        float4 v1 = *(const float4*)(sp + 4);
        unsigned short h[8] = { f2b(v0.x), f2b(v0.y), f2b(v0.z), f2b(v0.w),
                                f2b(v1.x), f2b(v1.y), f2b(v1.z), f2b(v1.w) };
        *(uint4*)(wedgep + (size_t)i*8) = *(uint4*)h;
    } else if (b < CVT4_BLOCKS + EMB4_BLOCKS + GEOM_BLOCKS + WCOMB_BLOCKS + WFC2_BLOCKS + WPACKE_BLOCKS + WPACK1_BLOCKS) {
        // W1 fragment pack (3 layers): i2 = lp*8192 + f*512 + wv*128 + j*64 + lane
        int wb = b - (CVT4_BLOCKS + EMB4_BLOCKS + GEOM_BLOCKS + WCOMB_BLOCKS + WFC2_BLOCKS + WPACKE_BLOCKS);
        int i2 = wb*256 + t;                 // 0..24575
        int lp = i2 >> 13;                   // 0..2
        int e = i2 & 8191;
        int lane = e & 63, j = (e >> 6) & 1, wv = (e >> 7) & 3, f = e >> 9;
        int row = f*64 + wv*16 + (lane & 15);
        int col = j*32 + (lane >> 4)*8;
        const float* sp = W1 + (size_t)lp*65536 + (size_t)row*64 + col;
        float4 v0 = *(const float4*)sp;
        float4 v1 = *(const float4*)(sp + 4);
        unsigned short h[8] = { f2b(v0.x), f2b(v0.y), f2b(v0.z), f2b(v0.w),
                                f2b(v1.x), f2b(v1.y), f2b(v1.z), f2b(v1.w) };
        *(uint4*)(w1p + (size_t)i2*8) = *(uint4*)h;
    } else {
        int lp = 1 + (t >> 7);
        int row = t & 127;
        const float* b2l = b2 + (lp-1)*256;
        const float* wmrow = (row < 64) ? (Wsrc + (size_t)lp*16384 + row*256)
                                        : (Wdst + (size_t)lp*16384 + (row-64)*256);
        float acc = 0.f;
        for (int c = 0; c < 256; ++c) acc += wmrow[c] * b2l[c];
        acc += (row < 64) ? bsrc[lp*64 + row] : bdst[lp*64 + (row-64)];
        bcomb[(lp-1)*128 + row] = acc;
        if (t == 0) {
            float bo = 0.f;
            const float* b23 = b2 + 2*256;
            for (int c = 0; c < 256; ++c) bo += Wfc[c] * b23[c];
            out[0] = bo + bfc[0];
        }
    }
}

// ---------------- merged eproj + layer0 xj/xi GEMM ----------------
#define EPITCH 264
#define APITCH 40
#define MCP 72
__global__ __launch_bounds__(256) void eplg_kernel(
    const unsigned short* __restrict__ Bwp,  // PACKED Wedge frags
    const float* __restrict__ bias,          // bedge [192]
    const float* __restrict__ dvec,          // [E]
    unsigned short* __restrict__ C,          // eproj out [E,192]
    const unsigned short* __restrict__ A,    // d_x [N,256]
    const unsigned short* __restrict__ B1g,  // wsrc [64,256]
    const unsigned short* __restrict__ B2g,  // wdst [64,256]
    const float* __restrict__ bias1,         // bsrc
    const float* __restrict__ bias2,         // bdst
    unsigned short* __restrict__ Cg) {       // d_xjxi [N,128]
    __shared__ __align__(16) unsigned short sm[64*EPITCH];   // 33792 B (union)
    const int t = threadIdx.x;
    const int w = t >> 6, lane = t & 63, lr = lane & 15, lq = lane >> 4;

    if (blockIdx.x < 1500) {
        // ================= eproj =================
        unsigned short* As = sm;
        const int m0 = blockIdx.x * 64;
        const int arow = t >> 2, achk = t & 3;

        float dv = dvec[m0 + arow];
        const float gamma = 31.875f;
        const float step  = 8.0f / 255.0f;
        #pragma unroll
        for (int c32 = 0; c32 < 8; ++c32) {
            int kb = c32*32 + achk*8;
            unsigned short h[8];
            #pragma unroll
            for (int j = 0; j < 8; ++j) {
                float tt = dv - (float)(kb+j)*step;
                h[j] = f2b(__expf(-gamma*tt*tt));
            }
            *(uint4*)(&As[arow*EPITCH + kb]) = *(uint4*)h;
        }
        __syncthreads();

        const unsigned short* Bp = Bwp + (size_t)w*12288 + lane*8;

        floatx4 acc[4][3] = {};
        uint4 pb[3];
        #pragma unroll
        for (int ns = 0; ns < 3; ++ns)
            pb[ns] = *(const uint4*)(Bp + ns*4096);

        for (int k0 = 0; k0 < 256; k0 += 32) {
            int ks = k0 >> 5;
            uint4 cb[3];
            cb[0] = pb[0]; cb[1] = pb[1]; cb[2] = pb[2];
            if (k0 + 32 < 256) {
                #pragma unroll
                for (int ns = 0; ns < 3; ++ns)
                    pb[ns] = *(const uint4*)(Bp + ns*4096 + (ks+1)*512);
            }
            bf16x8 af[4];
            #pragma unroll
            for (int mi = 0; mi < 4; ++mi)
                af[mi] = *(const bf16x8*)(&As[(mi*16 + lr)*EPITCH + k0 + lq*8]);
            #pragma unroll
            for (int mi = 0; mi < 4; ++mi) {
                #pragma unroll
                for (int ns = 0; ns < 3; ++ns)
                    acc[mi][ns] = __builtin_amdgcn_mfma_f32_16x16x32_bf16(
                        af[mi], *(const bf16x8*)&cb[ns], acc[mi][ns], 0, 0, 0);
            }
        }

        #pragma unroll
        for (int ns = 0; ns < 3; ++ns) {
            int bc = 48*w + ns*16 + lr;
            float bv = bias[bc];
            #pragma unroll
            for (int mi = 0; mi < 4; ++mi) {
                #pragma unroll
                for (int rg = 0; rg < 4; ++rg) {
                    int row = m0 + mi*16 + lq*4 + rg;
                    C[(size_t)row*192 + bc] = f2b(acc[mi][ns][rg] + bv);
                }
            }
        }
        return;
    }
    // ================= layer0 dual-B GEMM (K=256, M=6000) =================
    {
        unsigned short* As = sm;          // 64*40
        unsigned short* Bs = sm + 2560;   // 64*40
        unsigned short* Cs = sm;          // 64*72 epilogue reuse
        const int bid2 = blockIdx.x - 1500;
        const int bx = bid2 & 1;
        const int m0 = (bid2 >> 1) * 64;
        const unsigned short* B = bx ? B2g : B1g;
        const float* biasl = bx ? bias2 : bias1;
        const int n0 = bx * 64;
        const int K = 256, M = N_NODES, lda = 256, ldb = 256, ldc = 128;

        const int arow = t >> 2, achk = t & 3;

        floatx4 acc[4] = {};
        uint4 pa, pb;
        {
            int gm = m0 + arow;
            pa = (gm < M) ? *(const uint4*)(A + (size_t)gm*lda + achk*8) : make_uint4(0,0,0,0);
        }
        pb = *(const uint4*)(B + (size_t)arow*ldb + achk*8);

        for (int k0 = 0; k0 < K; k0 += 32) {
            *(uint4*)(&As[arow*APITCH + achk*8]) = pa;
            *(uint4*)(&Bs[arow*APITCH + achk*8]) = pb;
            __syncthreads();
            if (k0 + 32 < K) {
                int kn = k0 + 32;
                int gm = m0 + arow;
                pa = (gm < M) ? *(const uint4*)(A + (size_t)gm*lda + kn + achk*8) : make_uint4(0,0,0,0);
                pb = *(const uint4*)(B + (size_t)arow*ldb + kn + achk*8);
            }
            bf16x8 af, bfr[4];
            af = *(const bf16x8*)(&As[(w*16 + lr)*APITCH + lq*8]);
            #pragma unroll
            for (int ns = 0; ns < 4; ++ns)
                bfr[ns] = *(const bf16x8*)(&Bs[(ns*16 + lr)*APITCH + lq*8]);
            #pragma unroll
            for (int ns = 0; ns < 4; ++ns)
                acc[ns] = __builtin_amdgcn_mfma_f32_16x16x32_bf16(af, bfr[ns], acc[ns], 0,0,0);
            __syncthreads();
        }
        #pragma unroll
        for (int ns = 0; ns < 4; ++ns) {
            int bc = ns*16 + lr;
            float bv = biasl[bc];
            #pragma unroll
            for (int rg = 0; rg < 4; ++rg) {
                int lrow = w*16 + lq*4 + rg;
                Cs[lrow*MCP + bc] = f2b(acc[ns][rg] + bv);
            }
        }
        __syncthreads();
        #pragma unroll
        for (int it = 0; it < 2; ++it) {
            int i = t + it*256;
            int row = i >> 3, c8 = i & 7;
            int gm = m0 + row;
            if (gm < M)
                *(uint4*)(Cg + (size_t)gm*ldc + n0 + c8*8) = *(const uint4*)(Cs + row*MCP + c8*8);
        }
    }
}

// ---------------- fused FF + wcomb with PACKED weight fragments ----------------
#define HP 72
#define CP2 136
__global__ __launch_bounds__(256) void ffw_kernel(
    const unsigned short* __restrict__ XN,   // [N,64] bf16
    const unsigned short* __restrict__ W1p,  // PACKED W1 frags (this layer)
    const float* __restrict__ b1l,           // [1024]
    const unsigned short* __restrict__ WCp,  // PACKED wcomb frags (this layer)
    const float* __restrict__ bcl,           // [128]
    unsigned short* __restrict__ XO,         // [N,128] bf16
    int M) {
    __shared__ __align__(16) unsigned short s_h[16*HP];    // h chunk [16][72]
    __shared__ __align__(16) unsigned short s_c[16*CP2];   // epilogue [16][136]
    const int t = threadIdx.x;
    const int wv = t >> 6, lane = t & 63, lr = lane & 15, lq = lane >> 4;
    const int m0 = blockIdx.x * 16;

    int ga = m0 + lr;
    bool aok = ga < M;
    uint4 a0 = aok ? *(const uint4*)(XN + (size_t)ga*64 + lq*8) : make_uint4(0,0,0,0);
    uint4 a1 = aok ? *(const uint4*)(XN + (size_t)ga*64 + 32 + lq*8) : make_uint4(0,0,0,0);

    floatx4 acc2[2] = {};

    const unsigned short* W1b = W1p + (size_t)wv*1024 + lane*8;   // + f*4096 + j*512
    const unsigned short* WCb = WCp + (size_t)wv*2048 + lane*8;   // + f*8192 + ns*1024 + j*512

    uint4 pb1[2], pb2[4];
    pb1[0] = *(const uint4*)(W1b);
    pb1[1] = *(const uint4*)(W1b + 512);
    pb2[0] = *(const uint4*)(WCb);
    pb2[1] = *(const uint4*)(WCb + 512);
    pb2[2] = *(const uint4*)(WCb + 1024);
    pb2[3] = *(const uint4*)(WCb + 1536);

    for (int f = 0; f < 16; ++f) {
        uint4 cb1_0 = pb1[0], cb1_1 = pb1[1];
        uint4 cb2_0 = pb2[0], cb2_1 = pb2[1], cb2_2 = pb2[2], cb2_3 = pb2[3];
        float bv1 = b1l[f*64 + wv*16 + lr];
        if (f < 15) {
            const unsigned short* n1 = W1b + (f+1)*4096;
            const unsigned short* n2 = WCb + (f+1)*8192;
            pb1[0] = *(const uint4*)(n1);
            pb1[1] = *(const uint4*)(n1 + 512);
            pb2[0] = *(const uint4*)(n2);
            pb2[1] = *(const uint4*)(n2 + 512);
            pb2[2] = *(const uint4*)(n2 + 1024);
            pb2[3] = *(const uint4*)(n2 + 1536);
        }
        floatx4 hacc = {};
        hacc = __builtin_amdgcn_mfma_f32_16x16x32_bf16(
            *(const bf16x8*)&a0, *(const bf16x8*)&cb1_0, hacc, 0,0,0);
        hacc = __builtin_amdgcn_mfma_f32_16x16x32_bf16(
            *(const bf16x8*)&a1, *(const bf16x8*)&cb1_1, hacc, 0,0,0);
        {
            int col = wv*16 + lr;
            #pragma unroll
            for (int rg = 0; rg < 4; ++rg) {
                int row = lq*4 + rg;
                s_h[row*HP + col] = f2b(silu_f(hacc[rg] + bv1));
            }
        }
        __syncthreads();
        bf16x8 ha0 = *(const bf16x8*)(&s_h[lr*HP + lq*8]);
        bf16x8 ha1 = *(const bf16x8*)(&s_h[lr*HP + 32 + lq*8]);
        acc2[0] = __builtin_amdgcn_mfma_f32_16x16x32_bf16(ha0, *(const bf16x8*)&cb2_0, acc2[0], 0,0,0);
        acc2[0] = __builtin_amdgcn_mfma_f32_16x16x32_bf16(ha1, *(const bf16x8*)&cb2_1, acc2[0], 0,0,0);
        acc2[1] = __builtin_amdgcn_mfma_f32_16x16x32_bf16(ha0, *(const bf16x8*)&cb2_2, acc2[1], 0,0,0);
        acc2[1] = __builtin_amdgcn_mfma_f32_16x16x32_bf16(ha1, *(const bf16x8*)&cb2_3, acc2[1], 0,0,0);
        __syncthreads();
    }

    #pragma unroll
    for (int ns = 0; ns < 2; ++ns) {
        int col = wv*32 + ns*16 + lr;
        float bv = bcl[col];
        #pragma unroll
        for (int rg = 0; rg < 4; ++rg) {
            int row = lq*4 + rg;
            s_c[row*CP2 + col] = f2b(acc2[ns][rg] + bv);
        }
    }
    __syncthreads();
    {
        int row = t >> 4, c8 = t & 15;
        int gm = m0 + row;
        if (gm < M)
            *(uint4*)(XO + (size_t)gm*128 + c8*8) = *(const uint4*)(s_c + row*CP2 + c8*8);
    }
}

// ---------------- layer-2 FF + fused final reduction (packed W1, barrier-free loop) ----------------
__global__ __launch_bounds__(256) void ffa_kernel(
    const unsigned short* __restrict__ XN,   // [N,64] bf16
    const unsigned short* __restrict__ W1p,  // PACKED W1 frags (layer 2)
    const float* __restrict__ b1l,           // [1024]
    const float* __restrict__ wfc2,          // [1024]
    float* __restrict__ out, int M) {
    __shared__ float red[256];
    const int t = threadIdx.x;
    const int wv = t >> 6, lane = t & 63, lr = lane & 15, lq = lane >> 4;
    const int m0 = blockIdx.x * 16;

    int ga = m0 + lr;
    bool aok = ga < M;
    uint4 a0 = aok ? *(const uint4*)(XN + (size_t)ga*64 + lq*8) : make_uint4(0,0,0,0);
    uint4 a1 = aok ? *(const uint4*)(XN + (size_t)ga*64 + 32 + lq*8) : make_uint4(0,0,0,0);

    const unsigned short* W1b = W1p + (size_t)wv*1024 + lane*8;
    uint4 pb0 = *(const uint4*)(W1b);
    uint4 pb1 = *(const uint4*)(W1b + 512);

    float partial = 0.f;
    for (int f = 0; f < 16; ++f) {
        uint4 c0 = pb0, c1 = pb1;
        if (f < 15) {
            pb0 = *(const uint4*)(W1b + (f+1)*4096);
            pb1 = *(const uint4*)(W1b + (f+1)*4096 + 512);
        }
        floatx4 hacc = {};
        hacc = __builtin_amdgcn_mfma_f32_16x16x32_bf16(
            *(const bf16x8*)&a0, *(const bf16x8*)&c0, hacc, 0,0,0);
        hacc = __builtin_amdgcn_mfma_f32_16x16x32_bf16(
            *(const bf16x8*)&a1, *(const bf16x8*)&c1, hacc, 0,0,0);
        float bv1 = b1l[f*64 + wv*16 + lr];
        float wvv = wfc2[f*64 + wv*16 + lr];
        #pragma unroll
        for (int rg = 0; rg < 4; ++rg) {
            int gm = m0 + lq*4 + rg;
            if (gm < M) partial += silu_f(hacc[rg] + bv1) * wvv;
        }
    }
    red[t] = partial;
    __syncthreads();
    for (int off = 128; off > 0; off >>= 1) {
        if (t < off) red[t] += red[t+off];
        __syncthreads();
    }
    if (t == 0) atomicAdd(out, red[0] * (1.0f/(float)N_NODES));
}

// ---------------- angle attention v2: ONE node per block, split-k Chebyshev logits ----------------
// Logit critical path halved: pair (p,q) handled by 2 adjacent lanes (k in [0,32) / [32,64)),
// half 1 seeds T32/T33 via doubling identities (10 FMAs), partners combine via shfl_xor(1).
__global__ __launch_bounds__(256) void angle_kernel(
    const unsigned short* __restrict__ xjxi,
    const unsigned short* __restrict__ eproj,
    const float* __restrict__ rhat,
    const int*   __restrict__ src,
    const float* __restrict__ attn,
    unsigned short* __restrict__ xn) {
    __shared__ __align__(16) float s_xij[16][68];
    __shared__ float s_rhat[16][4];
    __shared__ float s_logit[16][17];
    __shared__ float s_e[16][17];
    __shared__ float s_m[16], s_zi[16];
    __shared__ float s_w[16];
    const int tt = threadIdx.x;
    const int node = blockIdx.x;

    if (tt < 16) {
        float4 rv = *(const float4*)(rhat + (size_t)(node*DEG_ + tt)*4);
        s_rhat[tt][0] = rv.x; s_rhat[tt][1] = rv.y; s_rhat[tt][2] = rv.z; s_rhat[tt][3] = 0.f;
        s_e[tt][tt] = 0.f;
    }
    {
        int p = tt >> 4, c4 = tt & 15;    // 256 threads: 16 edges x 16 chunks of 4 elems
        int e = node*DEG_ + p;
        int se = src[e];
        ushort4 aj = *(const ushort4*)(xjxi + (size_t)se*128 + c4*4);
        ushort4 ai = *(const ushort4*)(xjxi + (size_t)node*128 + 64 + c4*4);
        ushort4 ae = *(const ushort4*)(eproj + (size_t)e*192 + c4*4);
        s_xij[p][c4*4+0] = b2f(aj.x) + b2f(ai.x) + b2f(ae.x);
        s_xij[p][c4*4+1] = b2f(aj.y) + b2f(ai.y) + b2f(ae.y);
        s_xij[p][c4*4+2] = b2f(aj.z) + b2f(ai.z) + b2f(ae.z);
        s_xij[p][c4*4+3] = b2f(aj.w) + b2f(ai.w) + b2f(ae.w);
    }
    __syncthreads();
    int pp = 0, qq = 0;
    float lg = 0.f;
    if (tt < 240) {
        int pair = tt >> 1, half = tt & 1;
        pp = (int)((1.0f + sqrtf(8.0f*(float)pair + 1.0f)) * 0.5f);
        qq = pair - ((pp*(pp-1)) >> 1);
        float c = s_rhat[pp][0]*s_rhat[qq][0] + s_rhat[pp][1]*s_rhat[qq][1]
                + s_rhat[pp][2]*s_rhat[qq][2];
        c = fminf(fmaxf(c, -0.999999f), 0.999999f);
        float c2 = 2.0f * c;
        float tk0, tk1;
        if (half) {
            // seeds T32, T33 via T_2n = 2T_n^2 - 1 and T_{m+n} = 2 T_m T_n - T_{m-n}
            float T2  = fmaf(c2, c, -1.0f);
            float T3  = fmaf(2.0f*T2,  c,   -c);
            float T4  = fmaf(2.0f*T2,  T2,  -1.0f);
            float T7  = fmaf(2.0f*T4,  T3,  -c);
            float T8  = fmaf(2.0f*T4,  T4,  -1.0f);
            float T15 = fmaf(2.0f*T8,  T7,  -c);
            float T16 = fmaf(2.0f*T8,  T8,  -1.0f);
            float T31 = fmaf(2.0f*T16, T15, -c);
            float T32 = fmaf(2.0f*T16, T16, -1.0f);
            float T33 = fmaf(2.0f*T32, c,   -T31);
            tk0 = T32; tk1 = T33;
        } else {
            tk0 = 1.0f; tk1 = c;
        }
        const float* xp = &s_xij[pp][0] + half*32;
        const float* xq = &s_xij[qq][0] + half*32;
        const float* at = attn + half*32;
        float acc = 0.f;
        #pragma unroll
        for (int k0 = 0; k0 < 32; k0 += 4) {
            float4 xp4 = *(const float4*)(xp + k0);
            float4 xq4 = *(const float4*)(xq + k0);
            float a0 = at[k0+0], a1 = at[k0+1], a2 = at[k0+2], a3 = at[k0+3];
            float v0 = tk0 + xp4.x + xq4.x;
            acc = fmaf(a0, silu_f(v0), acc);
            { float tn2 = c2*tk1 - tk0; tk0 = tk1; tk1 = tn2; }
            float v1 = tk0 + xp4.y + xq4.y;
            acc = fmaf(a1, silu_f(v1), acc);
            { float tn2 = c2*tk1 - tk0; tk0 = tk1; tk1 = tn2; }
            float v2 = tk0 + xp4.z + xq4.z;
            acc = fmaf(a2, silu_f(v2), acc);
            { float tn2 = c2*tk1 - tk0; tk0 = tk1; tk1 = tn2; }
            float v3 = tk0 + xp4.w + xq4.w;
            acc = fmaf(a3, silu_f(v3), acc);
            { float tn2 = c2*tk1 - tk0; tk0 = tk1; tk1 = tn2; }
        }
        lg = acc;
    }
    lg += __shfl_xor(lg, 1);
    if (tt < 240 && (tt & 1) == 0) {
        s_logit[pp][qq] = lg;
        s_logit[qq][pp] = lg;
    }
    __syncthreads();
    if (tt < 16) {
        int q = tt;
        float mx = -1e30f;
        #pragma unroll
        for (int p = 0; p < 16; ++p) if (p != q) mx = fmaxf(mx, s_logit[p][q]);
        s_m[q] = mx;
    }
    __syncthreads();
    if (tt < 120) {
        int p2 = (int)((1.0f + sqrtf(8.0f*(float)tt + 1.0f)) * 0.5f);
        int q2 = tt - ((p2*(p2-1)) >> 1);
        float l = s_logit[p2][q2];
        s_e[p2][q2] = __expf(l - s_m[q2]);
        s_e[q2][p2] = __expf(l - s_m[p2]);
    }
    __syncthreads();
    if (tt < 16) {
        int q = tt;
        float z = 0.f;
        #pragma unroll
        for (int p = 0; p < 16; ++p) z += s_e[p][q];
        s_zi[q] = __builtin_amdgcn_rcpf(z);
    }
    __syncthreads();
    if (tt < 16) {
        int p = tt;
        float sw = 0.f;
        #pragma unroll
        for (int q = 0; q < 16; ++q) sw += s_e[p][q] * s_zi[q];
        s_w[p] = sw;
    }
    __syncthreads();
    if (tt < 64) {
        float acc = 0.f;
        #pragma unroll
        for (int p = 0; p < 16; ++p) acc += s_w[p] * s_xij[p][tt];
        xn[(size_t)node*64 + tt] = f2b(acc);
    }
}

extern "C" void kernel_launch(void* const* d_in, const int* in_sizes, int n_in,
                              void* d_out, int out_size, void* d_ws, size_t ws_size,
                              hipStream_t stream) {
    (void)in_sizes; (void)n_in; (void)out_size; (void)ws_size;
    const float* r    = (const float*)d_in[0];
    const int*   an   = (const int*)  d_in[1];
    const int*   src  = (const int*)  d_in[2];
    const float* emb  = (const float*)d_in[6];
    const float* Wsrc = (const float*)d_in[7];
    const float* bsrc = (const float*)d_in[8];
    const float* Wdst = (const float*)d_in[9];
    const float* bdst = (const float*)d_in[10];
    const float* Wedge= (const float*)d_in[11];
    const float* bedge= (const float*)d_in[12];
    const float* attn = (const float*)d_in[13];
    const float* W1   = (const float*)d_in[14];
    const float* b1   = (const float*)d_in[15];
    const float* W2   = (const float*)d_in[16];
    const float* b2   = (const float*)d_in[17];
    const float* Wfc  = (const float*)d_in[18];
    const float* bfc  = (const float*)d_in[19];

    char* ws = (char*)d_ws;
    float* d_d              = (float*)(ws);                    // 384000 B
    float* d_rhat           = (float*)(ws + 384000);           // 1536000 B
    unsigned short* wbf     = (unsigned short*)(ws + 1920000); // 196608 B (wsrc/wdst bf16)
    unsigned short* d_x     = (unsigned short*)(ws + 4180992); // 3072000 B
    unsigned short* d_xjxi  = (unsigned short*)(ws + 7252992); // 1536000 B
    unsigned short* d_eproj = (unsigned short*)(ws + 8788992); // 36864000 B
    unsigned short* d_xn    = (unsigned short*)(ws + 45652992);// 768000 B
    unsigned short* d_wcomb = (unsigned short*)(ws + 46420992);// 524288 B (packed)
    float* d_bcomb          = (float*)(ws + 46945280);         // 1024 B
    float* d_wfc2           = (float*)(ws + 46946304);         // 4096 B
    unsigned short* d_wedgep= (unsigned short*)(ws + 46950400);// 98304 B (packed)
    unsigned short* d_w1p   = (unsigned short*)(ws + 47048704);// 393216 B (packed, 3 layers)
    float* out = (float*)d_out;

    unsigned short* wsrc_bf  = wbf + WSRC_OFF;
    unsigned short* wdst_bf  = wbf + WDST_OFF;

    prep_kernel<<<CVT4_BLOCKS + EMB4_BLOCKS + GEOM_BLOCKS + WCOMB_BLOCKS + WFC2_BLOCKS
                  + WPACKE_BLOCKS + WPACK1_BLOCKS + 1, 256, 0, stream>>>(
        Wsrc, bsrc, Wdst, bdst, Wedge, W1, W2, b2, Wfc, bfc,
        wbf, an, emb, d_x, r, d_d, d_rhat, d_wcomb, d_bcomb, d_wfc2,
        d_wedgep, d_w1p, out);

    // merged eproj (packed Wedge) + layer0 xj/xi GEMM
    eplg_kernel<<<1500 + 188, 256, 0, stream>>>(
        d_wedgep, bedge, d_d, d_eproj,
        d_x, wsrc_bf, wdst_bf, bsrc, bdst, d_xjxi);

    // ---- layer 0 ----
    angle_kernel<<<N_NODES, 256, 0, stream>>>(
        d_xjxi, d_eproj, d_rhat, src, attn, d_xn);
    ffw_kernel<<<375, 256, 0, stream>>>(
        d_xn, d_w1p, b1, d_wcomb, d_bcomb, d_xjxi, N_NODES);

    // ---- layer 1 ----
    angle_kernel<<<N_NODES, 256, 0, stream>>>(
        d_xjxi, d_eproj + 64, d_rhat, src, attn + 64, d_xn);
    ffw_kernel<<<375, 256, 0, stream>>>(
        d_xn, d_w1p + 65536, b1 + 1024, d_wcomb + 131072, d_bcomb + 128, d_xjxi, N_NODES);

    // ---- layer 2 (FF + final reduction, packed W1, barrier-free loop) ----
    angle_kernel<<<N_NODES, 256, 0, stream>>>(
        d_xjxi, d_eproj + 128, d_rhat, src, attn + 128, d_xn);
    ffa_kernel<<<375, 256, 0, stream>>>(
        d_xn, d_w1p + 131072, b1 + 2048, d_wfc2, out, N_NODES);
}

// Round 9
// 239.601 us; speedup vs baseline: 1.3055x; 1.0490x over previous
//
#include <hip/hip_runtime.h>

#define N_NODES 6000
#define DEG_    16
#define N_EDGES (N_NODES*DEG_)
#define D_MODEL 256
#define D_MSG   64
#define D_FF    1024

typedef __bf16 bf16x8 __attribute__((ext_vector_type(8)));
typedef float floatx4 __attribute__((ext_vector_type(4)));

__device__ __forceinline__ float silu_f(float v) {
    return v * __builtin_amdgcn_rcpf(1.0f + __expf(-v));
}
__device__ __forceinline__ float b2f(unsigned short u) {
    union { unsigned int i; float f; } v; v.i = ((unsigned int)u) << 16; return v.f;
}
__device__ __forceinline__ unsigned short f2b(float f) {
    union { float f; unsigned int i; } v; v.f = f;
    unsigned int r = (v.i + 0x7FFFu + ((v.i >> 16) & 1u)) >> 16;
    return (unsigned short)r;
}

// ---------------- prep (fast branches only): weight cvt + embed + geom + frag packs ----------------
#define WSRC_OFF 0
#define WDST_OFF 49152
#define WCVT_TOTAL 98304
#define CVT4_BLOCKS (WCVT_TOTAL/4/256)         // 96
#define EMB4_BLOCKS (N_NODES*D_MODEL/4/256)    // 1500
#define GEOM_BLOCKS (N_EDGES/256)              // 375
#define WPACKE_BLOCKS 24                       // Wedge pack: 6144 lane-frags
#define WPACK1_BLOCKS 96                       // W1 pack (3 layers): 24576 lane-frags
__global__ __launch_bounds__(256) void prep_kernel(
    const float* __restrict__ Wsrc, const float* __restrict__ Wdst,
    const float* __restrict__ Wedge, const float* __restrict__ W1,
    unsigned short* __restrict__ wbf_out,
    const int* __restrict__ an, const float* __restrict__ emb,
    unsigned short* __restrict__ x,
    const float* __restrict__ r, float* __restrict__ d, float* __restrict__ rhat,
    unsigned short* __restrict__ wedgep,     // PACKED [6144 frags][8]
    unsigned short* __restrict__ w1p) {      // PACKED [3 layers][8192 frags][8]
    int b = blockIdx.x;
    int t = threadIdx.x;
    if (b < CVT4_BLOCKS) {
        int i = (b*256 + t) * 4;
        const float* sp = (i < WDST_OFF) ? (Wsrc + i) : (Wdst + (i - WDST_OFF));
        float4 v = *(const float4*)sp;
        *(ushort4*)(wbf_out + i) = make_ushort4(f2b(v.x), f2b(v.y), f2b(v.z), f2b(v.w));
    } else if (b < CVT4_BLOCKS + EMB4_BLOCKS) {
        int i4 = (b - CVT4_BLOCKS)*256 + t;
        int node = i4 >> 6, c4 = i4 & 63;
        float4 v = *(const float4*)(emb + (size_t)an[node]*D_MODEL + c4*4);
        *(ushort4*)(x + (size_t)node*D_MODEL + c4*4) =
            make_ushort4(f2b(v.x), f2b(v.y), f2b(v.z), f2b(v.w));
    } else if (b < CVT4_BLOCKS + EMB4_BLOCKS + GEOM_BLOCKS) {
        int e = (b - CVT4_BLOCKS - EMB4_BLOCKS)*256 + t;
        float xx = r[e*3+0], yy = r[e*3+1], zz = r[e*3+2];
        float n = sqrtf(xx*xx + yy*yy + zz*zz);
        d[e] = n;
        float inv = 1.0f / n;
        *(float4*)(rhat + (size_t)e*4) = make_float4(xx*inv, yy*inv, zz*inv, 0.f);
    } else if (b < CVT4_BLOCKS + EMB4_BLOCKS + GEOM_BLOCKS + WPACKE_BLOCKS) {
        // Wedge fragment pack: i = ((w*3+ns)*8+ks)*64 + lane, i in [0,6144)
        int wb = b - (CVT4_BLOCKS + EMB4_BLOCKS + GEOM_BLOCKS);
        int i = wb*256 + t;                  // 0..6143
        int lane = i & 63, ks = (i >> 6) & 7, rem = i >> 9;   // rem 0..11
        int ns = rem % 3, w = rem / 3;                        // w 0..3
        int row = 48*w + ns*16 + (lane & 15);
        int col = ks*32 + (lane >> 4)*8;
        const float* sp = Wedge + (size_t)row*256 + col;
        float4 v0 = *(const float4*)sp;
        float4 v1 = *(const float4*)(sp + 4);
        unsigned short h[8] = { f2b(v0.x), f2b(v0.y), f2b(v0.z), f2b(v0.w),
                                f2b(v1.x), f2b(v1.y), f2b(v1.z), f2b(v1.w) };
        *(uint4*)(wedgep + (size_t)i*8) = *(uint4*)h;
    } else {
        // W1 fragment pack (3 layers): i2 = lp*8192 + f*512 + wv*128 + j*64 + lane
        int wb = b - (CVT4_BLOCKS + EMB4_BLOCKS + GEOM_BLOCKS + WPACKE_BLOCKS);
        int i2 = wb*256 + t;                 // 0..24575
        int lp = i2 >> 13;                   // 0..2
        int e = i2 & 8191;
        int lane = e & 63, j = (e >> 6) & 1, wv = (e >> 7) & 3, f = e >> 9;
        int row = f*64 + wv*16 + (lane & 15);
        int col = j*32 + (lane >> 4)*8;
        const float* sp = W1 + (size_t)lp*65536 + (size_t)row*64 + col;
        float4 v0 = *(const float4*)sp;
        float4 v1 = *(const float4*)(sp + 4);
        unsigned short h[8] = { f2b(v0.x), f2b(v0.y), f2b(v0.z), f2b(v0.w),
                                f2b(v1.x), f2b(v1.y), f2b(v1.z), f2b(v1.w) };
        *(uint4*)(w1p + (size_t)i2*8) = *(uint4*)h;
    }
}

// ---------------- wcomb/wfc2/bcomb precompute (slow branches, moved off prep's critical path) ----
// WCOMB restructured: 4 rows/block (64 blocks) -> each W2 float4 load feeds 16 FMAs,
// 4x less redundant L2 traffic, unroll-8 deepens the load pipeline.
__global__ __launch_bounds__(256) void wcomb_kernel(
    const float* __restrict__ Wsrc, const float* __restrict__ bsrc,
    const float* __restrict__ Wdst, const float* __restrict__ bdst,
    const float* __restrict__ W2, const float* __restrict__ b2,
    const float* __restrict__ Wfc, const float* __restrict__ bfc,
    unsigned short* __restrict__ wcomb,      // PACKED [2 layers][16384 frags][8]
    float* __restrict__ bcomb,
    float* __restrict__ wfc2,
    float* __restrict__ out) {
    int b = blockIdx.x;
    int t = threadIdx.x;
    if (b < 64) {
        int lp  = 1 + (b >> 5);              // layer index 1,2
        int wb2 = b & 31;                    // 32 blocks/layer
        const float* W2f = W2 + (size_t)(lp-1)*262144;
        const float* wm[4];
        #pragma unroll
        for (int i = 0; i < 4; ++i) {
            int row = wb2*4 + i;
            wm[i] = (row < 64) ? (Wsrc + (size_t)lp*16384 + row*256)
                               : (Wdst + (size_t)lp*16384 + (row-64)*256);
        }
        float acc[4][4] = {};
        int c0 = t*4;
        #pragma unroll 8
        for (int c = 0; c < 256; ++c) {
            float4 w2v = *(const float4*)(W2f + (size_t)c*1024 + c0);
            #pragma unroll
            for (int i = 0; i < 4; ++i) {
                float w = wm[i][c];
                acc[i][0] = fmaf(w, w2v.x, acc[i][0]);
                acc[i][1] = fmaf(w, w2v.y, acc[i][1]);
                acc[i][2] = fmaf(w, w2v.z, acc[i][2]);
                acc[i][3] = fmaf(w, w2v.w, acc[i][3]);
            }
        }
        // packed store: ushort off = fc*8192 + wv*2048 + ns*1024 + j*512 + (lq*16+lr)*8 + cpos
        int fc = t >> 4, j = (t >> 3) & 1, lq = (t >> 1) & 3, cpos = (t & 1) * 4;
        #pragma unroll
        for (int i = 0; i < 4; ++i) {
            int row = wb2*4 + i;
            int wv = row >> 5, ns = (row >> 4) & 1, lr = row & 15;
            *(ushort4*)(wcomb + (size_t)(lp-1)*131072
                        + (size_t)fc*8192 + wv*2048 + ns*1024 + j*512 + (lq*16+lr)*8 + cpos) =
                make_ushort4(f2b(acc[i][0]), f2b(acc[i][1]), f2b(acc[i][2]), f2b(acc[i][3]));
        }
    } else if (b < 68) {
        int c = (b - 64)*256 + t;
        const float* W2f = W2 + 2*262144;
        float a0 = 0.f, a1 = 0.f, a2 = 0.f, a3 = 0.f;
        #pragma unroll 4
        for (int k = 0; k < 256; k += 4) {
            a0 = fmaf(Wfc[k+0], W2f[(size_t)(k+0)*1024 + c], a0);
            a1 = fmaf(Wfc[k+1], W2f[(size_t)(k+1)*1024 + c], a1);
            a2 = fmaf(Wfc[k+2], W2f[(size_t)(k+2)*1024 + c], a2);
            a3 = fmaf(Wfc[k+3], W2f[(size_t)(k+3)*1024 + c], a3);
        }
        wfc2[c] = (a0 + a1) + (a2 + a3);
    } else {
        int lp = 1 + (t >> 7);
        int row = t & 127;
        const float* b2l = b2 + (lp-1)*256;
        const float* wmrow = (row < 64) ? (Wsrc + (size_t)lp*16384 + row*256)
                                        : (Wdst + (size_t)lp*16384 + (row-64)*256);
        float acc = 0.f;
        #pragma unroll 8
        for (int c = 0; c < 256; ++c) acc += wmrow[c] * b2l[c];
        acc += (row < 64) ? bsrc[lp*64 + row] : bdst[lp*64 + (row-64)];
        bcomb[(lp-1)*128 + row] = acc;
        if (t == 0) {
            float bo = 0.f;
            const float* b23 = b2 + 2*256;
            #pragma unroll 8
            for (int c = 0; c < 256; ++c) bo += Wfc[c] * b23[c];
            out[0] = bo + bfc[0];
        }
    }
}

// ---------------- merged eproj + layer0 xj/xi GEMM ----------------
#define EPITCH 264
#define APITCH 40
#define MCP 72
__global__ __launch_bounds__(256) void eplg_kernel(
    const unsigned short* __restrict__ Bwp,  // PACKED Wedge frags
    const float* __restrict__ bias,          // bedge [192]
    const float* __restrict__ dvec,          // [E]
    unsigned short* __restrict__ C,          // eproj out [E,192]
    const unsigned short* __restrict__ A,    // d_x [N,256]
    const unsigned short* __restrict__ B1g,  // wsrc [64,256]
    const unsigned short* __restrict__ B2g,  // wdst [64,256]
    const float* __restrict__ bias1,         // bsrc
    const float* __restrict__ bias2,         // bdst
    unsigned short* __restrict__ Cg) {       // d_xjxi [N,128]
    __shared__ __align__(16) unsigned short sm[64*EPITCH];   // 33792 B (union)
    const int t = threadIdx.x;
    const int w = t >> 6, lane = t & 63, lr = lane & 15, lq = lane >> 4;

    if (blockIdx.x < 1500) {
        // ================= eproj =================
        unsigned short* As = sm;
        const int m0 = blockIdx.x * 64;
        const int arow = t >> 2, achk = t & 3;

        float dv = dvec[m0 + arow];
        const float gamma = 31.875f;
        const float step  = 8.0f / 255.0f;
        #pragma unroll
        for (int c32 = 0; c32 < 8; ++c32) {
            int kb = c32*32 + achk*8;
            unsigned short h[8];
            #pragma unroll
            for (int j = 0; j < 8; ++j) {
                float tt = dv - (float)(kb+j)*step;
                h[j] = f2b(__expf(-gamma*tt*tt));
            }
            *(uint4*)(&As[arow*EPITCH + kb]) = *(uint4*)h;
        }
        __syncthreads();

        const unsigned short* Bp = Bwp + (size_t)w*12288 + lane*8;

        floatx4 acc[4][3] = {};
        uint4 pb[3];
        #pragma unroll
        for (int ns = 0; ns < 3; ++ns)
            pb[ns] = *(const uint4*)(Bp + ns*4096);

        for (int k0 = 0; k0 < 256; k0 += 32) {
            int ks = k0 >> 5;
            uint4 cb[3];
            cb[0] = pb[0]; cb[1] = pb[1]; cb[2] = pb[2];
            if (k0 + 32 < 256) {
                #pragma unroll
                for (int ns = 0; ns < 3; ++ns)
                    pb[ns] = *(const uint4*)(Bp + ns*4096 + (ks+1)*512);
            }
            bf16x8 af[4];
            #pragma unroll
            for (int mi = 0; mi < 4; ++mi)
                af[mi] = *(const bf16x8*)(&As[(mi*16 + lr)*EPITCH + k0 + lq*8]);
            #pragma unroll
            for (int mi = 0; mi < 4; ++mi) {
                #pragma unroll
                for (int ns = 0; ns < 3; ++ns)
                    acc[mi][ns] = __builtin_amdgcn_mfma_f32_16x16x32_bf16(
                        af[mi], *(const bf16x8*)&cb[ns], acc[mi][ns], 0, 0, 0);
            }
        }

        #pragma unroll
        for (int ns = 0; ns < 3; ++ns) {
            int bc = 48*w + ns*16 + lr;
            float bv = bias[bc];
            #pragma unroll
            for (int mi = 0; mi < 4; ++mi) {
                #pragma unroll
                for (int rg = 0; rg < 4; ++rg) {
                    int row = m0 + mi*16 + lq*4 + rg;
                    C[(size_t)row*192 + bc] = f2b(acc[mi][ns][rg] + bv);
                }
            }
        }
        return;
    }
    // ================= layer0 dual-B GEMM (K=256, M=6000) =================
    {
        unsigned short* As = sm;          // 64*40
        unsigned short* Bs = sm + 2560;   // 64*40
        unsigned short* Cs = sm;          // 64*72 epilogue reuse
        const int bid2 = blockIdx.x - 1500;
        const int bx = bid2 & 1;
        const int m0 = (bid2 >> 1) * 64;
        const unsigned short* B = bx ? B2g : B1g;
        const float* biasl = bx ? bias2 : bias1;
        const int n0 = bx * 64;
        const int K = 256, M = N_NODES, lda = 256, ldb = 256, ldc = 128;

        const int arow = t >> 2, achk = t & 3;

        floatx4 acc[4] = {};
        uint4 pa, pb;
        {
            int gm = m0 + arow;
            pa = (gm < M) ? *(const uint4*)(A + (size_t)gm*lda + achk*8) : make_uint4(0,0,0,0);
        }
        pb = *(const uint4*)(B + (size_t)arow*ldb + achk*8);

        for (int k0 = 0; k0 < K; k0 += 32) {
            *(uint4*)(&As[arow*APITCH + achk*8]) = pa;
            *(uint4*)(&Bs[arow*APITCH + achk*8]) = pb;
            __syncthreads();
            if (k0 + 32 < K) {
                int kn = k0 + 32;
                int gm = m0 + arow;
                pa = (gm < M) ? *(const uint4*)(A + (size_t)gm*lda + kn + achk*8) : make_uint4(0,0,0,0);
                pb = *(const uint4*)(B + (size_t)arow*ldb + kn + achk*8);
            }
            bf16x8 af, bfr[4];
            af = *(const bf16x8*)(&As[(w*16 + lr)*APITCH + lq*8]);
            #pragma unroll
            for (int ns = 0; ns < 4; ++ns)
                bfr[ns] = *(const bf16x8*)(&Bs[(ns*16 + lr)*APITCH + lq*8]);
            #pragma unroll
            for (int ns = 0; ns < 4; ++ns)
                acc[ns] = __builtin_amdgcn_mfma_f32_16x16x32_bf16(af, bfr[ns], acc[ns], 0,0,0);
            __syncthreads();
        }
        #pragma unroll
        for (int ns = 0; ns < 4; ++ns) {
            int bc = ns*16 + lr;
            float bv = biasl[bc];
            #pragma unroll
            for (int rg = 0; rg < 4; ++rg) {
                int lrow = w*16 + lq*4 + rg;
                Cs[lrow*MCP + bc] = f2b(acc[ns][rg] + bv);
            }
        }
        __syncthreads();
        #pragma unroll
        for (int it = 0; it < 2; ++it) {
            int i = t + it*256;
            int row = i >> 3, c8 = i & 7;
            int gm = m0 + row;
            if (gm < M)
                *(uint4*)(Cg + (size_t)gm*ldc + n0 + c8*8) = *(const uint4*)(Cs + row*MCP + c8*8);
        }
    }
}

// ---------------- fused FF + wcomb with PACKED weight fragments ----------------
#define HP 72
#define CP2 136
__global__ __launch_bounds__(256) void ffw_kernel(
    const unsigned short* __restrict__ XN,   // [N,64] bf16
    const unsigned short* __restrict__ W1p,  // PACKED W1 frags (this layer)
    const float* __restrict__ b1l,           // [1024]
    const unsigned short* __restrict__ WCp,  // PACKED wcomb frags (this layer)
    const float* __restrict__ bcl,           // [128]
    unsigned short* __restrict__ XO,         // [N,128] bf16
    int M) {
    __shared__ __align__(16) unsigned short s_h[16*HP];    // h chunk [16][72]
    __shared__ __align__(16) unsigned short s_c[16*CP2];   // epilogue [16][136]
    const int t = threadIdx.x;
    const int wv = t >> 6, lane = t & 63, lr = lane & 15, lq = lane >> 4;
    const int m0 = blockIdx.x * 16;

    int ga = m0 + lr;
    bool aok = ga < M;
    uint4 a0 = aok ? *(const uint4*)(XN + (size_t)ga*64 + lq*8) : make_uint4(0,0,0,0);
    uint4 a1 = aok ? *(const uint4*)(XN + (size_t)ga*64 + 32 + lq*8) : make_uint4(0,0,0,0);

    floatx4 acc2[2] = {};

    const unsigned short* W1b = W1p + (size_t)wv*1024 + lane*8;   // + f*4096 + j*512
    const unsigned short* WCb = WCp + (size_t)wv*2048 + lane*8;   // + f*8192 + ns*1024 + j*512

    uint4 pb1[2], pb2[4];
    pb1[0] = *(const uint4*)(W1b);
    pb1[1] = *(const uint4*)(W1b + 512);
    pb2[0] = *(const uint4*)(WCb);
    pb2[1] = *(const uint4*)(WCb + 512);
    pb2[2] = *(const uint4*)(WCb + 1024);
    pb2[3] = *(const uint4*)(WCb + 1536);

    for (int f = 0; f < 16; ++f) {
        uint4 cb1_0 = pb1[0], cb1_1 = pb1[1];
        uint4 cb2_0 = pb2[0], cb2_1 = pb2[1], cb2_2 = pb2[2], cb2_3 = pb2[3];
        float bv1 = b1l[f*64 + wv*16 + lr];
        if (f < 15) {
            const unsigned short* n1 = W1b + (f+1)*4096;
            const unsigned short* n2 = WCb + (f+1)*8192;
            pb1[0] = *(const uint4*)(n1);
            pb1[1] = *(const uint4*)(n1 + 512);
            pb2[0] = *(const uint4*)(n2);
            pb2[1] = *(const uint4*)(n2 + 512);
            pb2[2] = *(const uint4*)(n2 + 1024);
            pb2[3] = *(const uint4*)(n2 + 1536);
        }
        floatx4 hacc = {};
        hacc = __builtin_amdgcn_mfma_f32_16x16x32_bf16(
            *(const bf16x8*)&a0, *(const bf16x8*)&cb1_0, hacc, 0,0,0);
        hacc = __builtin_amdgcn_mfma_f32_16x16x32_bf16(
            *(const bf16x8*)&a1, *(const bf16x8*)&cb1_1, hacc, 0,0,0);
        {
            int col = wv*16 + lr;
            #pragma unroll
            for (int rg = 0; rg < 4; ++rg) {
                int row = lq*4 + rg;
                s_h[row*HP + col] = f2b(silu_f(hacc[rg] + bv1));
            }
        }
        __syncthreads();
        bf16x8 ha0 = *(const bf16x8*)(&s_h[lr*HP + lq*8]);
        bf16x8 ha1 = *(const bf16x8*)(&s_h[lr*HP + 32 + lq*8]);
        acc2[0] = __builtin_amdgcn_mfma_f32_16x16x32_bf16(ha0, *(const bf16x8*)&cb2_0, acc2[0], 0,0,0);
        acc2[0] = __builtin_amdgcn_mfma_f32_16x16x32_bf16(ha1, *(const bf16x8*)&cb2_1, acc2[0], 0,0,0);
        acc2[1] = __builtin_amdgcn_mfma_f32_16x16x32_bf16(ha0, *(const bf16x8*)&cb2_2, acc2[1], 0,0,0);
        acc2[1] = __builtin_amdgcn_mfma_f32_16x16x32_bf16(ha1, *(const bf16x8*)&cb2_3, acc2[1], 0,0,0);
        __syncthreads();
    }

    #pragma unroll
    for (int ns = 0; ns < 2; ++ns) {
        int col = wv*32 + ns*16 + lr;
        float bv = bcl[col];
        #pragma unroll
        for (int rg = 0; rg < 4; ++rg) {
            int row = lq*4 + rg;
            s_c[row*CP2 + col] = f2b(acc2[ns][rg] + bv);
        }
    }
    __syncthreads();
    {
        int row = t >> 4, c8 = t & 15;
        int gm = m0 + row;
        if (gm < M)
            *(uint4*)(XO + (size_t)gm*128 + c8*8) = *(const uint4*)(s_c + row*CP2 + c8*8);
    }
}

// ---------------- layer-2 FF + fused final reduction (packed W1, barrier-free loop) ----------------
__global__ __launch_bounds__(256) void ffa_kernel(
    const unsigned short* __restrict__ XN,   // [N,64] bf16
    const unsigned short* __restrict__ W1p,  // PACKED W1 frags (layer 2)
    const float* __restrict__ b1l,           // [1024]
    const float* __restrict__ wfc2,          // [1024]
    float* __restrict__ out, int M) {
    __shared__ float red[256];
    const int t = threadIdx.x;
    const int wv = t >> 6, lane = t & 63, lr = lane & 15, lq = lane >> 4;
    const int m0 = blockIdx.x * 16;

    int ga = m0 + lr;
    bool aok = ga < M;
    uint4 a0 = aok ? *(const uint4*)(XN + (size_t)ga*64 + lq*8) : make_uint4(0,0,0,0);
    uint4 a1 = aok ? *(const uint4*)(XN + (size_t)ga*64 + 32 + lq*8) : make_uint4(0,0,0,0);

    const unsigned short* W1b = W1p + (size_t)wv*1024 + lane*8;
    uint4 pb0 = *(const uint4*)(W1b);
    uint4 pb1 = *(const uint4*)(W1b + 512);

    float partial = 0.f;
    for (int f = 0; f < 16; ++f) {
        uint4 c0 = pb0, c1 = pb1;
        if (f < 15) {
            pb0 = *(const uint4*)(W1b + (f+1)*4096);
            pb1 = *(const uint4*)(W1b + (f+1)*4096 + 512);
        }
        floatx4 hacc = {};
        hacc = __builtin_amdgcn_mfma_f32_16x16x32_bf16(
            *(const bf16x8*)&a0, *(const bf16x8*)&c0, hacc, 0,0,0);
        hacc = __builtin_amdgcn_mfma_f32_16x16x32_bf16(
            *(const bf16x8*)&a1, *(const bf16x8*)&c1, hacc, 0,0,0);
        float bv1 = b1l[f*64 + wv*16 + lr];
        float wvv = wfc2[f*64 + wv*16 + lr];
        #pragma unroll
        for (int rg = 0; rg < 4; ++rg) {
            int gm = m0 + lq*4 + rg;
            if (gm < M) partial += silu_f(hacc[rg] + bv1) * wvv;
        }
    }
    red[t] = partial;
    __syncthreads();
    for (int off = 128; off > 0; off >>= 1) {
        if (t < off) red[t] += red[t+off];
        __syncthreads();
    }
    if (t == 0) atomicAdd(out, red[0] * (1.0f/(float)N_NODES));
}

// ---------------- angle attention v2: ONE node per block, split-k Chebyshev logits ----------------
__global__ __launch_bounds__(256) void angle_kernel(
    const unsigned short* __restrict__ xjxi,
    const unsigned short* __restrict__ eproj,
    const float* __restrict__ rhat,
    const int*   __restrict__ src,
    const float* __restrict__ attn,
    unsigned short* __restrict__ xn) {
    __shared__ __align__(16) float s_xij[16][68];
    __shared__ float s_rhat[16][4];
    __shared__ float s_logit[16][17];
    __shared__ float s_e[16][17];
    __shared__ float s_m[16], s_zi[16];
    __shared__ float s_w[16];
    const int tt = threadIdx.x;
    const int node = blockIdx.x;

    if (tt < 16) {
        float4 rv = *(const float4*)(rhat + (size_t)(node*DEG_ + tt)*4);
        s_rhat[tt][0] = rv.x; s_rhat[tt][1] = rv.y; s_rhat[tt][2] = rv.z; s_rhat[tt][3] = 0.f;
        s_e[tt][tt] = 0.f;
    }
    {
        int p = tt >> 4, c4 = tt & 15;    // 256 threads: 16 edges x 16 chunks of 4 elems
        int e = node*DEG_ + p;
        int se = src[e];
        ushort4 aj = *(const ushort4*)(xjxi + (size_t)se*128 + c4*4);
        ushort4 ai = *(const ushort4*)(xjxi + (size_t)node*128 + 64 + c4*4);
        ushort4 ae = *(const ushort4*)(eproj + (size_t)e*192 + c4*4);
        s_xij[p][c4*4+0] = b2f(aj.x) + b2f(ai.x) + b2f(ae.x);
        s_xij[p][c4*4+1] = b2f(aj.y) + b2f(ai.y) + b2f(ae.y);
        s_xij[p][c4*4+2] = b2f(aj.z) + b2f(ai.z) + b2f(ae.z);
        s_xij[p][c4*4+3] = b2f(aj.w) + b2f(ai.w) + b2f(ae.w);
    }
    __syncthreads();
    int pp = 0, qq = 0;
    float lg = 0.f;
    if (tt < 240) {
        int pair = tt >> 1, half = tt & 1;
        pp = (int)((1.0f + sqrtf(8.0f*(float)pair + 1.0f)) * 0.5f);
        qq = pair - ((pp*(pp-1)) >> 1);
        float c = s_rhat[pp][0]*s_rhat[qq][0] + s_rhat[pp][1]*s_rhat[qq][1]
                + s_rhat[pp][2]*s_rhat[qq][2];
        c = fminf(fmaxf(c, -0.999999f), 0.999999f);
        float c2 = 2.0f * c;
        float tk0, tk1;
        if (half) {
            float T2  = fmaf(c2, c, -1.0f);
            float T3  = fmaf(2.0f*T2,  c,   -c);
            float T4  = fmaf(2.0f*T2,  T2,  -1.0f);
            float T7  = fmaf(2.0f*T4,  T3,  -c);
            float T8  = fmaf(2.0f*T4,  T4,  -1.0f);
            float T15 = fmaf(2.0f*T8,  T7,  -c);
            float T16 = fmaf(2.0f*T8,  T8,  -1.0f);
            float T31 = fmaf(2.0f*T16, T15, -c);
            float T32 = fmaf(2.0f*T16, T16, -1.0f);
            float T33 = fmaf(2.0f*T32, c,   -T31);
            tk0 = T32; tk1 = T33;
        } else {
            tk0 = 1.0f; tk1 = c;
        }
        const float* xp = &s_xij[pp][0] + half*32;
        const float* xq = &s_xij[qq][0] + half*32;
        const float* at = attn + half*32;
        float acc = 0.f;
        #pragma unroll
        for (int k0 = 0; k0 < 32; k0 += 4) {
            float4 xp4 = *(const float4*)(xp + k0);
            float4 xq4 = *(const float4*)(xq + k0);
            float a0 = at[k0+0], a1 = at[k0+1], a2 = at[k0+2], a3 = at[k0+3];
            float v0 = tk0 + xp4.x + xq4.x;
            acc = fmaf(a0, silu_f(v0), acc);
            { float tn2 = c2*tk1 - tk0; tk0 = tk1; tk1 = tn2; }
            float v1 = tk0 + xp4.y + xq4.y;
            acc = fmaf(a1, silu_f(v1), acc);
            { float tn2 = c2*tk1 - tk0; tk0 = tk1; tk1 = tn2; }
            float v2 = tk0 + xp4.z + xq4.z;
            acc = fmaf(a2, silu_f(v2), acc);
            { float tn2 = c2*tk1 - tk0; tk0 = tk1; tk1 = tn2; }
            float v3 = tk0 + xp4.w + xq4.w;
            acc = fmaf(a3, silu_f(v3), acc);
            { float tn2 = c2*tk1 - tk0; tk0 = tk1; tk1 = tn2; }
        }
        lg = acc;
    }
    lg += __shfl_xor(lg, 1);
    if (tt < 240 && (tt & 1) == 0) {
        s_logit[pp][qq] = lg;
        s_logit[qq][pp] = lg;
    }
    __syncthreads();
    if (tt < 16) {
        int q = tt;
        float mx = -1e30f;
        #pragma unroll
        for (int p = 0; p < 16; ++p) if (p != q) mx = fmaxf(mx, s_logit[p][q]);
        s_m[q] = mx;
    }
    __syncthreads();
    if (tt < 120) {
        int p2 = (int)((1.0f + sqrtf(8.0f*(float)tt + 1.0f)) * 0.5f);
        int q2 = tt - ((p2*(p2-1)) >> 1);
        float l = s_logit[p2][q2];
        s_e[p2][q2] = __expf(l - s_m[q2]);
        s_e[q2][p2] = __expf(l - s_m[p2]);
    }
    __syncthreads();
    if (tt < 16) {
        int q = tt;
        float z = 0.f;
        #pragma unroll
        for (int p = 0; p < 16; ++p) z += s_e[p][q];
        s_zi[q] = __builtin_amdgcn_rcpf(z);
    }
    __syncthreads();
    if (tt < 16) {
        int p = tt;
        float sw = 0.f;
        #pragma unroll
        for (int q = 0; q < 16; ++q) sw += s_e[p][q] * s_zi[q];
        s_w[p] = sw;
    }
    __syncthreads();
    if (tt < 64) {
        float acc = 0.f;
        #pragma unroll
        for (int p = 0; p < 16; ++p) acc += s_w[p] * s_xij[p][tt];
        xn[(size_t)node*64 + tt] = f2b(acc);
    }
}

extern "C" void kernel_launch(void* const* d_in, const int* in_sizes, int n_in,
                              void* d_out, int out_size, void* d_ws, size_t ws_size,
                              hipStream_t stream) {
    (void)in_sizes; (void)n_in; (void)out_size; (void)ws_size;
    const float* r    = (const float*)d_in[0];
    const int*   an   = (const int*)  d_in[1];
    const int*   src  = (const int*)  d_in[2];
    const float* emb  = (const float*)d_in[6];
    const float* Wsrc = (const float*)d_in[7];
    const float* bsrc = (const float*)d_in[8];
    const float* Wdst = (const float*)d_in[9];
    const float* bdst = (const float*)d_in[10];
    const float* Wedge= (const float*)d_in[11];
    const float* bedge= (const float*)d_in[12];
    const float* attn = (const float*)d_in[13];
    const float* W1   = (const float*)d_in[14];
    const float* b1   = (const float*)d_in[15];
    const float* W2   = (const float*)d_in[16];
    const float* b2   = (const float*)d_in[17];
    const float* Wfc  = (const float*)d_in[18];
    const float* bfc  = (const float*)d_in[19];

    char* ws = (char*)d_ws;
    float* d_d              = (float*)(ws);                    // 384000 B
    float* d_rhat           = (float*)(ws + 384000);           // 1536000 B
    unsigned short* wbf     = (unsigned short*)(ws + 1920000); // 196608 B (wsrc/wdst bf16)
    unsigned short* d_x     = (unsigned short*)(ws + 4180992); // 3072000 B
    unsigned short* d_xjxi  = (unsigned short*)(ws + 7252992); // 1536000 B
    unsigned short* d_eproj = (unsigned short*)(ws + 8788992); // 36864000 B
    unsigned short* d_xn    = (unsigned short*)(ws + 45652992);// 768000 B
    unsigned short* d_wcomb = (unsigned short*)(ws + 46420992);// 524288 B (packed)
    float* d_bcomb          = (float*)(ws + 46945280);         // 1024 B
    float* d_wfc2           = (float*)(ws + 46946304);         // 4096 B
    unsigned short* d_wedgep= (unsigned short*)(ws + 46950400);// 98304 B (packed)
    unsigned short* d_w1p   = (unsigned short*)(ws + 47048704);// 393216 B (packed, 3 layers)
    float* out = (float*)d_out;

    unsigned short* wsrc_bf  = wbf + WSRC_OFF;
    unsigned short* wdst_bf  = wbf + WDST_OFF;

    // fast prep (only what eplg needs) -> eplg starts ASAP
    prep_kernel<<<CVT4_BLOCKS + EMB4_BLOCKS + GEOM_BLOCKS + WPACKE_BLOCKS + WPACK1_BLOCKS,
                  256, 0, stream>>>(
        Wsrc, Wdst, Wedge, W1, wbf, an, emb, d_x, r, d_d, d_rhat, d_wedgep, d_w1p);

    // merged eproj (packed Wedge) + layer0 xj/xi GEMM
    eplg_kernel<<<1500 + 188, 256, 0, stream>>>(
        d_wedgep, bedge, d_d, d_eproj,
        d_x, wsrc_bf, wdst_bf, bsrc, bdst, d_xjxi);

    // wcomb/wfc2/bcomb precompute (needed only from ffw onward)
    wcomb_kernel<<<69, 256, 0, stream>>>(
        Wsrc, bsrc, Wdst, bdst, W2, b2, Wfc, bfc,
        d_wcomb, d_bcomb, d_wfc2, out);

    // ---- layer 0 ----
    angle_kernel<<<N_NODES, 256, 0, stream>>>(
        d_xjxi, d_eproj, d_rhat, src, attn, d_xn);
    ffw_kernel<<<375, 256, 0, stream>>>(
        d_xn, d_w1p, b1, d_wcomb, d_bcomb, d_xjxi, N_NODES);

    // ---- layer 1 ----
    angle_kernel<<<N_NODES, 256, 0, stream>>>(
        d_xjxi, d_eproj + 64, d_rhat, src, attn + 64, d_xn);
    ffw_kernel<<<375, 256, 0, stream>>>(
        d_xn, d_w1p + 65536, b1 + 1024, d_wcomb + 131072, d_bcomb + 128, d_xjxi, N_NODES);

    // ---- layer 2 (FF + final reduction, packed W1, barrier-free loop) ----
    angle_kernel<<<N_NODES, 256, 0, stream>>>(
        d_xjxi, d_eproj + 128, d_rhat, src, attn + 128, d_xn);
    ffa_kernel<<<375, 256, 0, stream>>>(
        d_xn, d_w1p + 131072, b1 + 2048, d_wfc2, out, N_NODES);
}

// Round 10
// 229.399 us; speedup vs baseline: 1.3636x; 1.0445x over previous
//
#include <hip/hip_runtime.h>

#define N_NODES 6000
#define DEG_    16
#define N_EDGES (N_NODES*DEG_)
#define D_MODEL 256
#define D_MSG   64
#define D_FF    1024

typedef __bf16 bf16x8 __attribute__((ext_vector_type(8)));
typedef float floatx4 __attribute__((ext_vector_type(4)));

__device__ __forceinline__ float silu_f(float v) {
    return v * __builtin_amdgcn_rcpf(1.0f + __expf(-v));
}
__device__ __forceinline__ float b2f(unsigned short u) {
    union { unsigned int i; float f; } v; v.i = ((unsigned int)u) << 16; return v.f;
}
__device__ __forceinline__ unsigned short f2b(float f) {
    union { float f; unsigned int i; } v; v.f = f;
    unsigned int r = (v.i + 0x7FFFu + ((v.i >> 16) & 1u)) >> 16;
    return (unsigned short)r;
}

// ---------------- prep (fast branches only): weight cvt + embed + geom + frag packs ----------------
#define WSRC_OFF 0
#define WDST_OFF 49152
#define WCVT_TOTAL 98304
#define CVT4_BLOCKS (WCVT_TOTAL/4/256)         // 96
#define EMB4_BLOCKS (N_NODES*D_MODEL/4/256)    // 1500
#define GEOM_BLOCKS (N_EDGES/256)              // 375
#define WPACKE_BLOCKS 24                       // Wedge pack: 6144 lane-frags
#define WPACK1_BLOCKS 96                       // W1 pack (3 layers): 24576 lane-frags
__global__ __launch_bounds__(256) void prep_kernel(
    const float* __restrict__ Wsrc, const float* __restrict__ Wdst,
    const float* __restrict__ Wedge, const float* __restrict__ W1,
    unsigned short* __restrict__ wbf_out,
    const int* __restrict__ an, const float* __restrict__ emb,
    unsigned short* __restrict__ x,
    const float* __restrict__ r, float* __restrict__ d, float* __restrict__ rhat,
    unsigned short* __restrict__ wedgep,     // PACKED [6144 frags][8]
    unsigned short* __restrict__ w1p) {      // PACKED [3 layers][8192 frags][8]
    int b = blockIdx.x;
    int t = threadIdx.x;
    if (b < CVT4_BLOCKS) {
        int i = (b*256 + t) * 4;
        const float* sp = (i < WDST_OFF) ? (Wsrc + i) : (Wdst + (i - WDST_OFF));
        float4 v = *(const float4*)sp;
        *(ushort4*)(wbf_out + i) = make_ushort4(f2b(v.x), f2b(v.y), f2b(v.z), f2b(v.w));
    } else if (b < CVT4_BLOCKS + EMB4_BLOCKS) {
        int i4 = (b - CVT4_BLOCKS)*256 + t;
        int node = i4 >> 6, c4 = i4 & 63;
        float4 v = *(const float4*)(emb + (size_t)an[node]*D_MODEL + c4*4);
        *(ushort4*)(x + (size_t)node*D_MODEL + c4*4) =
            make_ushort4(f2b(v.x), f2b(v.y), f2b(v.z), f2b(v.w));
    } else if (b < CVT4_BLOCKS + EMB4_BLOCKS + GEOM_BLOCKS) {
        int e = (b - CVT4_BLOCKS - EMB4_BLOCKS)*256 + t;
        float xx = r[e*3+0], yy = r[e*3+1], zz = r[e*3+2];
        float n = sqrtf(xx*xx + yy*yy + zz*zz);
        d[e] = n;
        float inv = 1.0f / n;
        *(float4*)(rhat + (size_t)e*4) = make_float4(xx*inv, yy*inv, zz*inv, 0.f);
    } else if (b < CVT4_BLOCKS + EMB4_BLOCKS + GEOM_BLOCKS + WPACKE_BLOCKS) {
        // Wedge fragment pack: i = ((w*3+ns)*8+ks)*64 + lane, i in [0,6144)
        int wb = b - (CVT4_BLOCKS + EMB4_BLOCKS + GEOM_BLOCKS);
        int i = wb*256 + t;                  // 0..6143
        int lane = i & 63, ks = (i >> 6) & 7, rem = i >> 9;   // rem 0..11
        int ns = rem % 3, w = rem / 3;                        // w 0..3
        int row = 48*w + ns*16 + (lane & 15);
        int col = ks*32 + (lane >> 4)*8;
        const float* sp = Wedge + (size_t)row*256 + col;
        float4 v0 = *(const float4*)sp;
        float4 v1 = *(const float4*)(sp + 4);
        unsigned short h[8] = { f2b(v0.x), f2b(v0.y), f2b(v0.z), f2b(v0.w),
                                f2b(v1.x), f2b(v1.y), f2b(v1.z), f2b(v1.w) };
        *(uint4*)(wedgep + (size_t)i*8) = *(uint4*)h;
    } else {
        // W1 fragment pack (3 layers): i2 = lp*8192 + f*512 + wv*128 + j*64 + lane
        int wb = b - (CVT4_BLOCKS + EMB4_BLOCKS + GEOM_BLOCKS + WPACKE_BLOCKS);
        int i2 = wb*256 + t;                 // 0..24575
        int lp = i2 >> 13;                   // 0..2
        int e = i2 & 8191;
        int lane = e & 63, j = (e >> 6) & 1, wv = (e >> 7) & 3, f = e >> 9;
        int row = f*64 + wv*16 + (lane & 15);
        int col = j*32 + (lane >> 4)*8;
        const float* sp = W1 + (size_t)lp*65536 + (size_t)row*64 + col;
        float4 v0 = *(const float4*)sp;
        float4 v1 = *(const float4*)(sp + 4);
        unsigned short h[8] = { f2b(v0.x), f2b(v0.y), f2b(v0.z), f2b(v0.w),
                                f2b(v1.x), f2b(v1.y), f2b(v1.z), f2b(v1.w) };
        *(uint4*)(w1p + (size_t)i2*8) = *(uint4*)h;
    }
}

// ---------------- merged eproj + layer0 xj/xi GEMM + wcomb/wfc2/bcomb precompute ----------------
// blocks [0,1500): eproj; [1500,1688): layer0 GEMM; [1688,1757): wcomb branch (no deps on prep,
// fills CUs during eproj tail; its inputs are raw fp32 weights).
#define EPITCH 264
#define APITCH 40
#define MCP 72
__global__ __launch_bounds__(256) void eplg_kernel(
    const unsigned short* __restrict__ Bwp,  // PACKED Wedge frags
    const float* __restrict__ bias,          // bedge [192]
    const float* __restrict__ dvec,          // [E]
    unsigned short* __restrict__ C,          // eproj out [E,192]
    const unsigned short* __restrict__ A,    // d_x [N,256]
    const unsigned short* __restrict__ B1g,  // wsrc [64,256] bf16
    const unsigned short* __restrict__ B2g,  // wdst [64,256] bf16
    const float* __restrict__ bias1,         // bsrc
    const float* __restrict__ bias2,         // bdst
    unsigned short* __restrict__ Cg,         // d_xjxi [N,128]
    const float* __restrict__ Wsrc, const float* __restrict__ Wdst,
    const float* __restrict__ W2, const float* __restrict__ b2,
    const float* __restrict__ Wfc, const float* __restrict__ bfc,
    unsigned short* __restrict__ wcomb,      // PACKED [2 layers][16384 frags][8]
    float* __restrict__ bcomb,
    float* __restrict__ wfc2,
    float* __restrict__ out) {
    __shared__ __align__(16) unsigned short sm[64*EPITCH];   // 33792 B (union)
    const int t = threadIdx.x;
    const int w = t >> 6, lane = t & 63, lr = lane & 15, lq = lane >> 4;

    if (blockIdx.x < 1500) {
        // ================= eproj =================
        unsigned short* As = sm;
        const int m0 = blockIdx.x * 64;
        const int arow = t >> 2, achk = t & 3;

        float dv = dvec[m0 + arow];
        const float gamma = 31.875f;
        const float step  = 8.0f / 255.0f;
        #pragma unroll
        for (int c32 = 0; c32 < 8; ++c32) {
            int kb = c32*32 + achk*8;
            unsigned short h[8];
            #pragma unroll
            for (int j = 0; j < 8; ++j) {
                float tt = dv - (float)(kb+j)*step;
                h[j] = f2b(__expf(-gamma*tt*tt));
            }
            *(uint4*)(&As[arow*EPITCH + kb]) = *(uint4*)h;
        }
        __syncthreads();

        const unsigned short* Bp = Bwp + (size_t)w*12288 + lane*8;

        floatx4 acc[4][3] = {};
        uint4 pb[3];
        #pragma unroll
        for (int ns = 0; ns < 3; ++ns)
            pb[ns] = *(const uint4*)(Bp + ns*4096);

        for (int k0 = 0; k0 < 256; k0 += 32) {
            int ks = k0 >> 5;
            uint4 cb[3];
            cb[0] = pb[0]; cb[1] = pb[1]; cb[2] = pb[2];
            if (k0 + 32 < 256) {
                #pragma unroll
                for (int ns = 0; ns < 3; ++ns)
                    pb[ns] = *(const uint4*)(Bp + ns*4096 + (ks+1)*512);
            }
            bf16x8 af[4];
            #pragma unroll
            for (int mi = 0; mi < 4; ++mi)
                af[mi] = *(const bf16x8*)(&As[(mi*16 + lr)*EPITCH + k0 + lq*8]);
            #pragma unroll
            for (int mi = 0; mi < 4; ++mi) {
                #pragma unroll
                for (int ns = 0; ns < 3; ++ns)
                    acc[mi][ns] = __builtin_amdgcn_mfma_f32_16x16x32_bf16(
                        af[mi], *(const bf16x8*)&cb[ns], acc[mi][ns], 0, 0, 0);
            }
        }

        #pragma unroll
        for (int ns = 0; ns < 3; ++ns) {
            int bc = 48*w + ns*16 + lr;
            float bv = bias[bc];
            #pragma unroll
            for (int mi = 0; mi < 4; ++mi) {
                #pragma unroll
                for (int rg = 0; rg < 4; ++rg) {
                    int row = m0 + mi*16 + lq*4 + rg;
                    C[(size_t)row*192 + bc] = f2b(acc[mi][ns][rg] + bv);
                }
            }
        }
        return;
    }
    if (blockIdx.x < 1688) {
        // ================= layer0 dual-B GEMM (K=256, M=6000) =================
        unsigned short* As = sm;          // 64*40
        unsigned short* Bs = sm + 2560;   // 64*40
        unsigned short* Cs = sm;          // 64*72 epilogue reuse
        const int bid2 = blockIdx.x - 1500;
        const int bx = bid2 & 1;
        const int m0 = (bid2 >> 1) * 64;
        const unsigned short* B = bx ? B2g : B1g;
        const float* biasl = bx ? bias2 : bias1;
        const int n0 = bx * 64;
        const int K = 256, M = N_NODES, lda = 256, ldb = 256, ldc = 128;

        const int arow = t >> 2, achk = t & 3;

        floatx4 acc[4] = {};
        uint4 pa, pb;
        {
            int gm = m0 + arow;
            pa = (gm < M) ? *(const uint4*)(A + (size_t)gm*lda + achk*8) : make_uint4(0,0,0,0);
        }
        pb = *(const uint4*)(B + (size_t)arow*ldb + achk*8);

        for (int k0 = 0; k0 < K; k0 += 32) {
            *(uint4*)(&As[arow*APITCH + achk*8]) = pa;
            *(uint4*)(&Bs[arow*APITCH + achk*8]) = pb;
            __syncthreads();
            if (k0 + 32 < K) {
                int kn = k0 + 32;
                int gm = m0 + arow;
                pa = (gm < M) ? *(const uint4*)(A + (size_t)gm*lda + kn + achk*8) : make_uint4(0,0,0,0);
                pb = *(const uint4*)(B + (size_t)arow*ldb + kn + achk*8);
            }
            bf16x8 af, bfr[4];
            af = *(const bf16x8*)(&As[(w*16 + lr)*APITCH + lq*8]);
            #pragma unroll
            for (int ns = 0; ns < 4; ++ns)
                bfr[ns] = *(const bf16x8*)(&Bs[(ns*16 + lr)*APITCH + lq*8]);
            #pragma unroll
            for (int ns = 0; ns < 4; ++ns)
                acc[ns] = __builtin_amdgcn_mfma_f32_16x16x32_bf16(af, bfr[ns], acc[ns], 0,0,0);
            __syncthreads();
        }
        #pragma unroll
        for (int ns = 0; ns < 4; ++ns) {
            int bc = ns*16 + lr;
            float bv = biasl[bc];
            #pragma unroll
            for (int rg = 0; rg < 4; ++rg) {
                int lrow = w*16 + lq*4 + rg;
                Cs[lrow*MCP + bc] = f2b(acc[ns][rg] + bv);
            }
        }
        __syncthreads();
        #pragma unroll
        for (int it = 0; it < 2; ++it) {
            int i = t + it*256;
            int row = i >> 3, c8 = i & 7;
            int gm = m0 + row;
            if (gm < M)
                *(uint4*)(Cg + (size_t)gm*ldc + n0 + c8*8) = *(const uint4*)(Cs + row*MCP + c8*8);
        }
        return;
    }
    // ================= wcomb/wfc2/bcomb branch =================
    {
        int b = blockIdx.x - 1688;       // 0..68
        if (b < 64) {
            int lp  = 1 + (b >> 5);      // layer index 1,2
            int wb2 = b & 31;            // 32 blocks/layer
            const float* W2f = W2 + (size_t)(lp-1)*262144;
            const float* wm[4];
            #pragma unroll
            for (int i = 0; i < 4; ++i) {
                int row = wb2*4 + i;
                wm[i] = (row < 64) ? (Wsrc + (size_t)lp*16384 + row*256)
                                   : (Wdst + (size_t)lp*16384 + (row-64)*256);
            }
            float acc[4][4] = {};
            int c0 = t*4;
            #pragma unroll 8
            for (int c = 0; c < 256; ++c) {
                float4 w2v = *(const float4*)(W2f + (size_t)c*1024 + c0);
                #pragma unroll
                for (int i = 0; i < 4; ++i) {
                    float wv2 = wm[i][c];
                    acc[i][0] = fmaf(wv2, w2v.x, acc[i][0]);
                    acc[i][1] = fmaf(wv2, w2v.y, acc[i][1]);
                    acc[i][2] = fmaf(wv2, w2v.z, acc[i][2]);
                    acc[i][3] = fmaf(wv2, w2v.w, acc[i][3]);
                }
            }
            int fc = t >> 4, j = (t >> 3) & 1, lq2 = (t >> 1) & 3, cpos = (t & 1) * 4;
            #pragma unroll
            for (int i = 0; i < 4; ++i) {
                int row = wb2*4 + i;
                int wv2 = row >> 5, ns = (row >> 4) & 1, lr2 = row & 15;
                *(ushort4*)(wcomb + (size_t)(lp-1)*131072
                            + (size_t)fc*8192 + wv2*2048 + ns*1024 + j*512 + (lq2*16+lr2)*8 + cpos) =
                    make_ushort4(f2b(acc[i][0]), f2b(acc[i][1]), f2b(acc[i][2]), f2b(acc[i][3]));
            }
        } else if (b < 68) {
            int c = (b - 64)*256 + t;
            const float* W2f = W2 + 2*262144;
            float a0 = 0.f, a1 = 0.f, a2 = 0.f, a3 = 0.f;
            #pragma unroll 4
            for (int k = 0; k < 256; k += 4) {
                a0 = fmaf(Wfc[k+0], W2f[(size_t)(k+0)*1024 + c], a0);
                a1 = fmaf(Wfc[k+1], W2f[(size_t)(k+1)*1024 + c], a1);
                a2 = fmaf(Wfc[k+2], W2f[(size_t)(k+2)*1024 + c], a2);
                a3 = fmaf(Wfc[k+3], W2f[(size_t)(k+3)*1024 + c], a3);
            }
            wfc2[c] = (a0 + a1) + (a2 + a3);
        } else {
            int lp = 1 + (t >> 7);
            int row = t & 127;
            const float* b2l = b2 + (lp-1)*256;
            const float* wmrow = (row < 64) ? (Wsrc + (size_t)lp*16384 + row*256)
                                            : (Wdst + (size_t)lp*16384 + (row-64)*256);
            float acc = 0.f;
            #pragma unroll 8
            for (int c = 0; c < 256; ++c) acc += wmrow[c] * b2l[c];
            acc += (row < 64) ? bias1[lp*64 + row] : bias2[lp*64 + (row-64)];
            bcomb[(lp-1)*128 + row] = acc;
            if (t == 0) {
                float bo = 0.f;
                const float* b23 = b2 + 2*256;
                #pragma unroll 8
                for (int c = 0; c < 256; ++c) bo += Wfc[c] * b23[c];
                out[0] = bo + bfc[0];
            }
        }
    }
}

// ---------------- fused FF + wcomb with PACKED weight fragments ----------------
#define HP 72
#define CP2 136
__global__ __launch_bounds__(256) void ffw_kernel(
    const unsigned short* __restrict__ XN,   // [N,64] bf16
    const unsigned short* __restrict__ W1p,  // PACKED W1 frags (this layer)
    const float* __restrict__ b1l,           // [1024]
    const unsigned short* __restrict__ WCp,  // PACKED wcomb frags (this layer)
    const float* __restrict__ bcl,           // [128]
    unsigned short* __restrict__ XO,         // [N,128] bf16
    int M) {
    __shared__ __align__(16) unsigned short s_h[16*HP];    // h chunk [16][72]
    __shared__ __align__(16) unsigned short s_c[16*CP2];   // epilogue [16][136]
    const int t = threadIdx.x;
    const int wv = t >> 6, lane = t & 63, lr = lane & 15, lq = lane >> 4;
    const int m0 = blockIdx.x * 16;

    int ga = m0 + lr;
    bool aok = ga < M;
    uint4 a0 = aok ? *(const uint4*)(XN + (size_t)ga*64 + lq*8) : make_uint4(0,0,0,0);
    uint4 a1 = aok ? *(const uint4*)(XN + (size_t)ga*64 + 32 + lq*8) : make_uint4(0,0,0,0);

    floatx4 acc2[2] = {};

    const unsigned short* W1b = W1p + (size_t)wv*1024 + lane*8;   // + f*4096 + j*512
    const unsigned short* WCb = WCp + (size_t)wv*2048 + lane*8;   // + f*8192 + ns*1024 + j*512

    uint4 pb1[2], pb2[4];
    pb1[0] = *(const uint4*)(W1b);
    pb1[1] = *(const uint4*)(W1b + 512);
    pb2[0] = *(const uint4*)(WCb);
    pb2[1] = *(const uint4*)(WCb + 512);
    pb2[2] = *(const uint4*)(WCb + 1024);
    pb2[3] = *(const uint4*)(WCb + 1536);

    for (int f = 0; f < 16; ++f) {
        uint4 cb1_0 = pb1[0], cb1_1 = pb1[1];
        uint4 cb2_0 = pb2[0], cb2_1 = pb2[1], cb2_2 = pb2[2], cb2_3 = pb2[3];
        float bv1 = b1l[f*64 + wv*16 + lr];
        if (f < 15) {
            const unsigned short* n1 = W1b + (f+1)*4096;
            const unsigned short* n2 = WCb + (f+1)*8192;
            pb1[0] = *(const uint4*)(n1);
            pb1[1] = *(const uint4*)(n1 + 512);
            pb2[0] = *(const uint4*)(n2);
            pb2[1] = *(const uint4*)(n2 + 512);
            pb2[2] = *(const uint4*)(n2 + 1024);
            pb2[3] = *(const uint4*)(n2 + 1536);
        }
        floatx4 hacc = {};
        hacc = __builtin_amdgcn_mfma_f32_16x16x32_bf16(
            *(const bf16x8*)&a0, *(const bf16x8*)&cb1_0, hacc, 0,0,0);
        hacc = __builtin_amdgcn_mfma_f32_16x16x32_bf16(
            *(const bf16x8*)&a1, *(const bf16x8*)&cb1_1, hacc, 0,0,0);
        {
            int col = wv*16 + lr;
            #pragma unroll
            for (int rg = 0; rg < 4; ++rg) {
                int row = lq*4 + rg;
                s_h[row*HP + col] = f2b(silu_f(hacc[rg] + bv1));
            }
        }
        __syncthreads();
        bf16x8 ha0 = *(const bf16x8*)(&s_h[lr*HP + lq*8]);
        bf16x8 ha1 = *(const bf16x8*)(&s_h[lr*HP + 32 + lq*8]);
        acc2[0] = __builtin_amdgcn_mfma_f32_16x16x32_bf16(ha0, *(const bf16x8*)&cb2_0, acc2[0], 0,0,0);
        acc2[0] = __builtin_amdgcn_mfma_f32_16x16x32_bf16(ha1, *(const bf16x8*)&cb2_1, acc2[0], 0,0,0);
        acc2[1] = __builtin_amdgcn_mfma_f32_16x16x32_bf16(ha0, *(const bf16x8*)&cb2_2, acc2[1], 0,0,0);
        acc2[1] = __builtin_amdgcn_mfma_f32_16x16x32_bf16(ha1, *(const bf16x8*)&cb2_3, acc2[1], 0,0,0);
        __syncthreads();
    }

    #pragma unroll
    for (int ns = 0; ns < 2; ++ns) {
        int col = wv*32 + ns*16 + lr;
        float bv = bcl[col];
        #pragma unroll
        for (int rg = 0; rg < 4; ++rg) {
            int row = lq*4 + rg;
            s_c[row*CP2 + col] = f2b(acc2[ns][rg] + bv);
        }
    }
    __syncthreads();
    {
        int row = t >> 4, c8 = t & 15;
        int gm = m0 + row;
        if (gm < M)
            *(uint4*)(XO + (size_t)gm*128 + c8*8) = *(const uint4*)(s_c + row*CP2 + c8*8);
    }
}

// ---------------- layer-2 FF + fused final reduction (packed W1, barrier-free loop) ----------------
__global__ __launch_bounds__(256) void ffa_kernel(
    const unsigned short* __restrict__ XN,   // [N,64] bf16
    const unsigned short* __restrict__ W1p,  // PACKED W1 frags (layer 2)
    const float* __restrict__ b1l,           // [1024]
    const float* __restrict__ wfc2,          // [1024]
    float* __restrict__ out, int M) {
    __shared__ float red[256];
    const int t = threadIdx.x;
    const int wv = t >> 6, lane = t & 63, lr = lane & 15, lq = lane >> 4;
    const int m0 = blockIdx.x * 16;

    int ga = m0 + lr;
    bool aok = ga < M;
    uint4 a0 = aok ? *(const uint4*)(XN + (size_t)ga*64 + lq*8) : make_uint4(0,0,0,0);
    uint4 a1 = aok ? *(const uint4*)(XN + (size_t)ga*64 + 32 + lq*8) : make_uint4(0,0,0,0);

    const unsigned short* W1b = W1p + (size_t)wv*1024 + lane*8;
    uint4 pb0 = *(const uint4*)(W1b);
    uint4 pb1 = *(const uint4*)(W1b + 512);

    float partial = 0.f;
    for (int f = 0; f < 16; ++f) {
        uint4 c0 = pb0, c1 = pb1;
        if (f < 15) {
            pb0 = *(const uint4*)(W1b + (f+1)*4096);
            pb1 = *(const uint4*)(W1b + (f+1)*4096 + 512);
        }
        floatx4 hacc = {};
        hacc = __builtin_amdgcn_mfma_f32_16x16x32_bf16(
            *(const bf16x8*)&a0, *(const bf16x8*)&c0, hacc, 0,0,0);
        hacc = __builtin_amdgcn_mfma_f32_16x16x32_bf16(
            *(const bf16x8*)&a1, *(const bf16x8*)&c1, hacc, 0,0,0);
        float bv1 = b1l[f*64 + wv*16 + lr];
        float wvv = wfc2[f*64 + wv*16 + lr];
        #pragma unroll
        for (int rg = 0; rg < 4; ++rg) {
            int gm = m0 + lq*4 + rg;
            if (gm < M) partial += silu_f(hacc[rg] + bv1) * wvv;
        }
    }
    red[t] = partial;
    __syncthreads();
    for (int off = 128; off > 0; off >>= 1) {
        if (t < off) red[t] += red[t+off];
        __syncthreads();
    }
    if (t == 0) atomicAdd(out, red[0] * (1.0f/(float)N_NODES));
}

// ---------------- angle attention v3: split-k logits + full-width shuffle softmax ----------------
// Softmax tail rewritten: all 256 threads active, 4-step shfl_xor reductions within 16-lane
// groups replace the serial 16-iter loops; zi folded into a[p][q]; 7 barriers -> 5.
__global__ __launch_bounds__(256) void angle_kernel(
    const unsigned short* __restrict__ xjxi,
    const unsigned short* __restrict__ eproj,
    const float* __restrict__ rhat,
    const int*   __restrict__ src,
    const float* __restrict__ attn,
    unsigned short* __restrict__ xn) {
    __shared__ __align__(16) float s_xij[16][68];
    __shared__ float s_rhat[16][4];
    __shared__ float s_logit[16][17];
    __shared__ float s_a[16][17];
    __shared__ float s_w[16];
    const int tt = threadIdx.x;
    const int node = blockIdx.x;

    if (tt < 16) {
        float4 rv = *(const float4*)(rhat + (size_t)(node*DEG_ + tt)*4);
        s_rhat[tt][0] = rv.x; s_rhat[tt][1] = rv.y; s_rhat[tt][2] = rv.z; s_rhat[tt][3] = 0.f;
        s_logit[tt][tt] = -1e30f;      // diag -> exp() == 0
    }
    {
        int p = tt >> 4, c4 = tt & 15;    // 256 threads: 16 edges x 16 chunks of 4 elems
        int e = node*DEG_ + p;
        int se = src[e];
        ushort4 aj = *(const ushort4*)(xjxi + (size_t)se*128 + c4*4);
        ushort4 ai = *(const ushort4*)(xjxi + (size_t)node*128 + 64 + c4*4);
        ushort4 ae = *(const ushort4*)(eproj + (size_t)e*192 + c4*4);
        s_xij[p][c4*4+0] = b2f(aj.x) + b2f(ai.x) + b2f(ae.x);
        s_xij[p][c4*4+1] = b2f(aj.y) + b2f(ai.y) + b2f(ae.y);
        s_xij[p][c4*4+2] = b2f(aj.z) + b2f(ai.z) + b2f(ae.z);
        s_xij[p][c4*4+3] = b2f(aj.w) + b2f(ai.w) + b2f(ae.w);
    }
    __syncthreads();
    int pp = 0, qq = 0;
    float lg = 0.f;
    if (tt < 240) {
        int pair = tt >> 1, half = tt & 1;
        pp = (int)((1.0f + sqrtf(8.0f*(float)pair + 1.0f)) * 0.5f);
        qq = pair - ((pp*(pp-1)) >> 1);
        float c = s_rhat[pp][0]*s_rhat[qq][0] + s_rhat[pp][1]*s_rhat[qq][1]
                + s_rhat[pp][2]*s_rhat[qq][2];
        c = fminf(fmaxf(c, -0.999999f), 0.999999f);
        float c2 = 2.0f * c;
        float tk0, tk1;
        if (half) {
            float T2  = fmaf(c2, c, -1.0f);
            float T3  = fmaf(2.0f*T2,  c,   -c);
            float T4  = fmaf(2.0f*T2,  T2,  -1.0f);
            float T7  = fmaf(2.0f*T4,  T3,  -c);
            float T8  = fmaf(2.0f*T4,  T4,  -1.0f);
            float T15 = fmaf(2.0f*T8,  T7,  -c);
            float T16 = fmaf(2.0f*T8,  T8,  -1.0f);
            float T31 = fmaf(2.0f*T16, T15, -c);
            float T32 = fmaf(2.0f*T16, T16, -1.0f);
            float T33 = fmaf(2.0f*T32, c,   -T31);
            tk0 = T32; tk1 = T33;
        } else {
            tk0 = 1.0f; tk1 = c;
        }
        const float* xp = &s_xij[pp][0] + half*32;
        const float* xq = &s_xij[qq][0] + half*32;
        const float* at = attn + half*32;
        float acc = 0.f;
        #pragma unroll
        for (int k0 = 0; k0 < 32; k0 += 4) {
            float4 xp4 = *(const float4*)(xp + k0);
            float4 xq4 = *(const float4*)(xq + k0);
            float a0 = at[k0+0], a1 = at[k0+1], a2 = at[k0+2], a3 = at[k0+3];
            float v0 = tk0 + xp4.x + xq4.x;
            acc = fmaf(a0, silu_f(v0), acc);
            { float tn2 = c2*tk1 - tk0; tk0 = tk1; tk1 = tn2; }
            float v1 = tk0 + xp4.y + xq4.y;
            acc = fmaf(a1, silu_f(v1), acc);
            { float tn2 = c2*tk1 - tk0; tk0 = tk1; tk1 = tn2; }
            float v2 = tk0 + xp4.z + xq4.z;
            acc = fmaf(a2, silu_f(v2), acc);
            { float tn2 = c2*tk1 - tk0; tk0 = tk1; tk1 = tn2; }
            float v3 = tk0 + xp4.w + xq4.w;
            acc = fmaf(a3, silu_f(v3), acc);
            { float tn2 = c2*tk1 - tk0; tk0 = tk1; tk1 = tn2; }
        }
        lg = acc;
    }
    lg += __shfl_xor(lg, 1);
    if (tt < 240 && (tt & 1) == 0) {
        s_logit[pp][qq] = lg;
        s_logit[qq][pp] = lg;
    }
    __syncthreads();
    // column softmax: thread (q = tt>>4, p = tt&15); shfl groups of 16 share q
    {
        int q = tt >> 4, p = tt & 15;
        float l = s_logit[p][q];
        float m = l;
        m = fmaxf(m, __shfl_xor(m, 1));
        m = fmaxf(m, __shfl_xor(m, 2));
        m = fmaxf(m, __shfl_xor(m, 4));
        m = fmaxf(m, __shfl_xor(m, 8));
        float e = __expf(l - m);
        float z = e;
        z += __shfl_xor(z, 1);
        z += __shfl_xor(z, 2);
        z += __shfl_xor(z, 4);
        z += __shfl_xor(z, 8);
        s_a[p][q] = e * __builtin_amdgcn_rcpf(z);   // attention weight, zi folded in
    }
    __syncthreads();
    // row-sum: thread (p = tt>>4, q = tt&15); sw[p] = sum_q a[p][q]
    {
        int p = tt >> 4, q = tt & 15;
        float a = s_a[p][q];
        a += __shfl_xor(a, 1);
        a += __shfl_xor(a, 2);
        a += __shfl_xor(a, 4);
        a += __shfl_xor(a, 8);
        if (q == 0) s_w[p] = a;
    }
    __syncthreads();
    if (tt < 64) {
        float acc = 0.f;
        #pragma unroll
        for (int p = 0; p < 16; ++p) acc += s_w[p] * s_xij[p][tt];
        xn[(size_t)node*64 + tt] = f2b(acc);
    }
}

extern "C" void kernel_launch(void* const* d_in, const int* in_sizes, int n_in,
                              void* d_out, int out_size, void* d_ws, size_t ws_size,
                              hipStream_t stream) {
    (void)in_sizes; (void)n_in; (void)out_size; (void)ws_size;
    const float* r    = (const float*)d_in[0];
    const int*   an   = (const int*)  d_in[1];
    const int*   src  = (const int*)  d_in[2];
    const float* emb  = (const float*)d_in[6];
    const float* Wsrc = (const float*)d_in[7];
    const float* bsrc = (const float*)d_in[8];
    const float* Wdst = (const float*)d_in[9];
    const float* bdst = (const float*)d_in[10];
    const float* Wedge= (const float*)d_in[11];
    const float* bedge= (const float*)d_in[12];
    const float* attn = (const float*)d_in[13];
    const float* W1   = (const float*)d_in[14];
    const float* b1   = (const float*)d_in[15];
    const float* W2   = (const float*)d_in[16];
    const float* b2   = (const float*)d_in[17];
    const float* Wfc  = (const float*)d_in[18];
    const float* bfc  = (const float*)d_in[19];

    char* ws = (char*)d_ws;
    float* d_d              = (float*)(ws);                    // 384000 B
    float* d_rhat           = (float*)(ws + 384000);           // 1536000 B
    unsigned short* wbf     = (unsigned short*)(ws + 1920000); // 196608 B (wsrc/wdst bf16)
    unsigned short* d_x     = (unsigned short*)(ws + 4180992); // 3072000 B
    unsigned short* d_xjxi  = (unsigned short*)(ws + 7252992); // 1536000 B
    unsigned short* d_eproj = (unsigned short*)(ws + 8788992); // 36864000 B
    unsigned short* d_xn    = (unsigned short*)(ws + 45652992);// 768000 B
    unsigned short* d_wcomb = (unsigned short*)(ws + 46420992);// 524288 B (packed)
    float* d_bcomb          = (float*)(ws + 46945280);         // 1024 B
    float* d_wfc2           = (float*)(ws + 46946304);         // 4096 B
    unsigned short* d_wedgep= (unsigned short*)(ws + 46950400);// 98304 B (packed)
    unsigned short* d_w1p   = (unsigned short*)(ws + 47048704);// 393216 B (packed, 3 layers)
    float* out = (float*)d_out;

    unsigned short* wsrc_bf  = wbf + WSRC_OFF;
    unsigned short* wdst_bf  = wbf + WDST_OFF;

    // fast prep (only what eplg needs) -> eplg starts ASAP
    prep_kernel<<<CVT4_BLOCKS + EMB4_BLOCKS + GEOM_BLOCKS + WPACKE_BLOCKS + WPACK1_BLOCKS,
                  256, 0, stream>>>(
        Wsrc, Wdst, Wedge, W1, wbf, an, emb, d_x, r, d_d, d_rhat, d_wedgep, d_w1p);

    // merged eproj + layer0 GEMM + wcomb precompute (wcomb blocks fill eproj's tail)
    eplg_kernel<<<1500 + 188 + 69, 256, 0, stream>>>(
        d_wedgep, bedge, d_d, d_eproj,
        d_x, wsrc_bf, wdst_bf, bsrc, bdst, d_xjxi,
        Wsrc, Wdst, W2, b2, Wfc, bfc,
        d_wcomb, d_bcomb, d_wfc2, out);

    // ---- layer 0 ----
    angle_kernel<<<N_NODES, 256, 0, stream>>>(
        d_xjxi, d_eproj, d_rhat, src, attn, d_xn);
    ffw_kernel<<<375, 256, 0, stream>>>(
        d_xn, d_w1p, b1, d_wcomb, d_bcomb, d_xjxi, N_NODES);

    // ---- layer 1 ----
    angle_kernel<<<N_NODES, 256, 0, stream>>>(
        d_xjxi, d_eproj + 64, d_rhat, src, attn + 64, d_xn);
    ffw_kernel<<<375, 256, 0, stream>>>(
        d_xn, d_w1p + 65536, b1 + 1024, d_wcomb + 131072, d_bcomb + 128, d_xjxi, N_NODES);

    // ---- layer 2 (FF + final reduction, packed W1, barrier-free loop) ----
    angle_kernel<<<N_NODES, 256, 0, stream>>>(
        d_xjxi, d_eproj + 128, d_rhat, src, attn + 128, d_xn);
    ffa_kernel<<<375, 256, 0, stream>>>(
        d_xn, d_w1p + 131072, b1 + 2048, d_wfc2, out, N_NODES);
}